// Round 8
// baseline (1441.613 us; speedup 1.0000x reference)
//
#include <hip/hip_runtime.h>

// ---------------- problem constants ----------------
#define BSZ   4096
#define NIN   3072
#define N1    1536
#define N2    256
#define NO    10
#define SEQ   128
#define CH    16            // timesteps per chunk
#define NCHUNK (SEQ/CH)

// dynamics constants
#define DVM  0.1f           // DT*TAU_MEM_INV
#define DIS  0.8f           // 1 - DT*TAU_SYN_INV
#define VTH  0.4f

// ---------------- workspace layout (bytes) ----------------
// [0, 67108864)        : inp1 (25MB) -> a2 (67MB per chunk) -> a3 (21MB)
// [67108864, ...)      : xfrag (75.5MB, dead after gemm1)  UNION  z1bits (100.7MB)
// [167772160, ...)     : w1frag (28.3MB, dead after gemm1) UNION  v2+i2+z2 (25.2MB)
// [196083712, ...)     : w2frag 3.1MB ; end 199229440
#define OFF_INP1 0
#define OFF_A2   0
#define OFF_A3   0
#define OFF_XF   67108864
#define OFF_Z1   67108864
#define OFF_W1F  167772160
#define OFF_V2   167772160
#define OFF_I2   171966464
#define OFF_Z2   176160768
#define OFF_W2F  196083712

typedef short bf16x8 __attribute__((ext_vector_type(8)));
typedef float f32x4  __attribute__((ext_vector_type(4)));

__device__ __forceinline__ void gload_lds16(const unsigned short* g, unsigned short* l) {
    __builtin_amdgcn_global_load_lds(
        (const __attribute__((address_space(1))) unsigned int*)g,
        (__attribute__((address_space(3))) unsigned int*)l, 16, 0, 0);
}

__device__ __forceinline__ unsigned short rne_bf16(float x) {
    unsigned u = __float_as_uint(x);
    return (unsigned short)((u + 0x7FFFu + ((u >> 16) & 1u)) >> 16);
}
__device__ __forceinline__ float bf2f(unsigned short h) {
    return __uint_as_float(((unsigned)h) << 16);
}

// ============ prep_x: 3-digit bf16 split of x, MFMA-fragment order ============
__global__ __launch_bounds__(256) void prep_x_kernel(
        const float* __restrict__ x, unsigned short* __restrict__ xf) {
    const int idx = blockIdx.x * 256 + threadIdx.x;
    const int lane = idx & 63;
    const int m16 = (idx >> 6) & 255;
    const int ks  = idx >> 14;                 // 0..95
    const int row = m16 * 16 + (lane & 15);
    const int k0  = ks * 32 + (lane >> 4) * 8;
    const float* src = x + (size_t)row * NIN + k0;
    union { unsigned short u[8]; bf16x8 v; } h, m, l;
    #pragma unroll
    for (int j = 0; j < 8; j++) {
        float v = src[j];
        h.u[j] = rne_bf16(v);
        float r1 = v - bf2f(h.u[j]);
        m.u[j] = rne_bf16(r1);
        float r2 = r1 - bf2f(m.u[j]);
        l.u[j] = rne_bf16(r2);
    }
    unsigned short* dst = xf + ((size_t)(ks * 256 + m16) * 3) * 512 + lane * 8;
    *(bf16x8*)(dst)        = h.v;
    *(bf16x8*)(dst + 512)  = m.v;
    *(bf16x8*)(dst + 1024) = l.v;
}

// ============ prep_w1: 3-digit split of W1, fragment order for LDS staging ============
__global__ __launch_bounds__(256) void prep_w1_kernel(
        const float* __restrict__ W1, unsigned short* __restrict__ wf) {
    const int idx = blockIdx.x * 256 + threadIdx.x;
    const int ks  = idx / 6144;                // 0..95
    const int rem = idx % 6144;
    const int n16 = rem >> 6;                  // 0..95
    const int lane = rem & 63;
    const int row = n16 * 16 + (lane & 15);
    const int k0  = ks * 32 + (lane >> 4) * 8;
    const float* src = W1 + (size_t)row * NIN + k0;
    union { unsigned short u[8]; bf16x8 v; } h, m, l;
    #pragma unroll
    for (int j = 0; j < 8; j++) {
        float v = src[j];
        h.u[j] = rne_bf16(v);
        float r1 = v - bf2f(h.u[j]);
        m.u[j] = rne_bf16(r1);
        float r2 = r1 - bf2f(m.u[j]);
        l.u[j] = rne_bf16(r2);
    }
    unsigned short* dst = wf + ((size_t)ks * 12 + (n16 >> 3)) * 12288
                             + (n16 & 7) * 1536 + lane * 8;
    *(bf16x8*)(dst)        = h.v;
    *(bf16x8*)(dst + 512)  = m.v;
    *(bf16x8*)(dst + 1024) = l.v;
}

// ============ GEMM1 via MFMA: inp1 = x @ W1.T + b1, 6-product digit split ============
__global__ __launch_bounds__(256, 2) void gemm1_mfma(
        const unsigned short* __restrict__ xf, const unsigned short* __restrict__ w1f,
        const float* __restrict__ b1, float* __restrict__ inp1) {
    __shared__ unsigned short Bs[2][12288];    // 2 x 24 KB
    const int tx = threadIdx.x;
    const int wave = tx >> 6, lane = tx & 63;
    const int wm = wave >> 1, wn = wave & 1;
    const int ln = lane & 15, ko = lane >> 4;
    const int bid = blockIdx.x;                // 384 blocks
    const int wg = (bid & 7) * 48 + (bid >> 3);   // XCD-chunked swizzle (384%8==0)
    const int mtile = wg / 12, ntile = wg % 12;
    const int m16b = mtile * 8 + wm * 4;

    f32x4 acc[4][4];
    #pragma unroll
    for (int mt = 0; mt < 4; mt++)
        #pragma unroll
        for (int nt = 0; nt < 4; nt++) acc[mt][nt] = (f32x4){0.f,0.f,0.f,0.f};

    const unsigned short* xfr = xf + lane * 8;

#define ALOAD(A_, ks_) do {                                                   \
    _Pragma("unroll")                                                         \
    for (int mt_ = 0; mt_ < 4; mt_++)                                         \
        _Pragma("unroll")                                                     \
        for (int d_ = 0; d_ < 3; d_++)                                        \
            A_[mt_][d_] = *(const bf16x8*)(xfr +                              \
                (((size_t)(ks_) * 256 + m16b + mt_) * 3 + d_) * 512);         \
} while (0)

#define STAGE1(ks_, buf_) do {                                                \
    const unsigned short* s_ = w1f + ((size_t)(ks_) * 12 + ntile) * 12288     \
                                   + wave * 3072 + lane * 8;                  \
    unsigned short* d_ = &Bs[buf_][wave * 3072];                              \
    _Pragma("unroll")                                                         \
    for (int j_ = 0; j_ < 6; j_++)                                            \
        gload_lds16(s_ + j_ * 512, d_ + j_ * 512);                            \
} while (0)

#define COMPUTE(A_, buf_) do {                                                \
    _Pragma("unroll")                                                         \
    for (int nt_ = 0; nt_ < 4; nt_++) {                                       \
        const unsigned short* bp_ = &Bs[buf_][(wn * 4 + nt_) * 1536 + lane * 8]; \
        bf16x8 bh_ = *(const bf16x8*)(bp_);                                   \
        bf16x8 bm_ = *(const bf16x8*)(bp_ + 512);                             \
        bf16x8 bl_ = *(const bf16x8*)(bp_ + 1024);                            \
        _Pragma("unroll")                                                     \
        for (int mt_ = 0; mt_ < 4; mt_++) {                                   \
            acc[mt_][nt_] = __builtin_amdgcn_mfma_f32_16x16x32_bf16(A_[mt_][0], bh_, acc[mt_][nt_], 0, 0, 0); \
            acc[mt_][nt_] = __builtin_amdgcn_mfma_f32_16x16x32_bf16(A_[mt_][1], bh_, acc[mt_][nt_], 0, 0, 0); \
            acc[mt_][nt_] = __builtin_amdgcn_mfma_f32_16x16x32_bf16(A_[mt_][2], bh_, acc[mt_][nt_], 0, 0, 0); \
            acc[mt_][nt_] = __builtin_amdgcn_mfma_f32_16x16x32_bf16(A_[mt_][0], bm_, acc[mt_][nt_], 0, 0, 0); \
            acc[mt_][nt_] = __builtin_amdgcn_mfma_f32_16x16x32_bf16(A_[mt_][1], bm_, acc[mt_][nt_], 0, 0, 0); \
            acc[mt_][nt_] = __builtin_amdgcn_mfma_f32_16x16x32_bf16(A_[mt_][0], bl_, acc[mt_][nt_], 0, 0, 0); \
        }                                                                     \
    }                                                                         \
} while (0)

    bf16x8 aA[4][3], aB[4][3];
    ALOAD(aA, 0);
    STAGE1(0, 0);
    __syncthreads();

    for (int ks = 0; ks < 96; ks += 2) {
        STAGE1(ks + 1, 1);
        ALOAD(aB, ks + 1);
        COMPUTE(aA, 0);
        __syncthreads();
        if (ks + 2 < 96) {
            STAGE1(ks + 2, 0);
            ALOAD(aA, ks + 2);
        }
        COMPUTE(aB, 1);
        __syncthreads();
    }

    // epilogue: C/D col=lane&15, row=(lane>>4)*4+r
    #pragma unroll
    for (int nt = 0; nt < 4; nt++) {
        const int n = ntile * 128 + wn * 64 + nt * 16 + ln;
        const float bias = b1[n];
        #pragma unroll
        for (int mt = 0; mt < 4; mt++) {
            #pragma unroll
            for (int r = 0; r < 4; r++) {
                const int m = mtile * 128 + wm * 64 + mt * 16 + ko * 4 + r;
                inp1[(size_t)m * N1 + n] = acc[mt][nt][r] + bias;
            }
        }
    }
#undef ALOAD
#undef STAGE1
#undef COMPUTE
}

// ============ LIF1: 128 timesteps; ballot mask captured via register select ============
// (known-good R5 form; writelane asm regressed numerics — CDNA SGPR hazard around
//  inline asm is not compiler-managed). layout z1a[b][w][t]; one coalesced 512B
//  store per wave per 64-t segment.
__global__ __launch_bounds__(256) void lif1_kernel(
        const float* __restrict__ inp1, unsigned long long* __restrict__ z1a) {
    const int b = blockIdx.y;
    const int n = blockIdx.x * 256 + threadIdx.x;
    const int lane = threadIdx.x & 63;
    const int w = n >> 6;                      // word index 0..23
    const float inp = inp1[(size_t)b * N1 + n];
    unsigned long long* obase = z1a + (size_t)b * 3072 + (size_t)w * 128;
    float v = 0.f, i = 0.f;
    #pragma unroll 1
    for (int seg = 0; seg < 2; seg++) {
        unsigned int plo = 0, phi = 0;
        #pragma unroll
        for (int tt = 0; tt < 64; tt++) {
            float vd = v + DVM * (i - v);
            bool z = (vd - VTH) > 0.f;
            unsigned long long m = __ballot(z);
            if (lane == tt) { plo = (unsigned int)m; phi = (unsigned int)(m >> 32); }
            v = z ? 0.f : vd;
            i = DIS * i + inp;
        }
        obase[seg * 64 + lane] = ((unsigned long long)phi << 32) | plo;
    }
}

// ============ W2 prep: split hi/lo bf16 in MFMA fragment order ============
__global__ __launch_bounds__(256) void prep_w2_kernel(
        const float* __restrict__ W2, unsigned short* __restrict__ frag) {
    const int idx = blockIdx.x * 256 + threadIdx.x;
    const int lane = idx & 63;
    const int ntg  = (idx >> 6) & 15;
    const int ks   = (idx >> 10) & 1;
    const int w    = idx >> 11;
    const int n = ntg * 16 + (lane & 15);
    const int k = w * 64 + ks * 32 + (lane >> 4) * 8;
    const int nblk = ntg >> 3, nt8 = ntg & 7;
    const size_t base = ((size_t)(w * 2 + nblk)) * 16384 + ks * 8192 + nt8 * 1024 + lane * 8;
    const float* src = W2 + (size_t)n * N1 + k;
    #pragma unroll
    for (int j = 0; j < 8; j++) {
        float x = src[j];
        unsigned short h = rne_bf16(x);
        frag[base + j] = h;
        float r = x - bf2f(h);
        frag[base + 512 + j] = rne_bf16(r);
    }
}

// byte (8 spike bits) -> 8 bf16 {0.0, 1.0}
__device__ __forceinline__ bf16x8 expand8(unsigned int byte) {
    union { unsigned int u[4]; bf16x8 v; } r;
    #pragma unroll
    for (int p = 0; p < 4; p++) {
        unsigned int lo = ((byte >> (2*p)) & 1u) * 0x3F80u;
        unsigned int hi = ((byte >> (2*p+1)) & 1u) * 0x3F80u;
        r.u[p] = lo | (hi << 16);
    }
    return r.v;
}

// ============ GEMM2: a2 = z1 @ (W2hi+W2lo).T + b2 via MFMA ============
// z1a layout: [b][w][t]. zw loads issued BEFORE staging so compiler waits
// vmcnt(8) for zw while next tile's global_load_lds stays in flight.
__global__ __launch_bounds__(256, 2) void gemm2_mfma(
        const unsigned long long* __restrict__ z1a,
        const unsigned short* __restrict__ w2frag,
        const float* __restrict__ b2, float* __restrict__ a2, int c) {
    __shared__ unsigned short Bs[2][16384];
    const int tx = threadIdx.x;
    const int wave = tx >> 6, lane = tx & 63;
    const int wm = wave >> 1, wn = wave & 1;
    const int ko = lane >> 4, ln = lane & 15;
    const int bm = blockIdx.x;
    const int bn = blockIdx.y;
    const int t_l = bm >> 4;
    const int b0 = (bm & 15) * 256 + wm * 128;
    const int t  = c * CH + t_l;

    f32x4 acc[8][4];
    #pragma unroll
    for (int mt = 0; mt < 8; mt++)
        #pragma unroll
        for (int nt = 0; nt < 4; nt++) acc[mt][nt] = (f32x4){0.f,0.f,0.f,0.f};

    const size_t zrowbase = (size_t)(b0 + ln) * 3072 + t;   // + row*3072 + w*128
    const unsigned short* sgbase = w2frag + (size_t)bn * 16384 + wave * 4096 + lane * 8;
    #define STAGE_B(w_, buf_) do {                                           \
        const unsigned short* s_ = sgbase + (size_t)(w_) * 32768;            \
        unsigned short* d_ = &Bs[buf_][wave * 4096];                         \
        _Pragma("unroll")                                                    \
        for (int j_ = 0; j_ < 8; j_++)                                       \
            gload_lds16(s_ + j_ * 512, d_ + j_ * 512);                       \
    } while (0)

    STAGE_B(0, 0);
    __syncthreads();

    for (int w = 0; w < 24; w++) {
        const int buf = w & 1;
        // zw loads FIRST (so their wait leaves staging outstanding)
        unsigned long long zw[8];
        #pragma unroll
        for (int mt = 0; mt < 8; mt++)
            zw[mt] = z1a[zrowbase + (size_t)(mt * 16) * 3072 + w * 128];
        if (w < 23) STAGE_B(w + 1, buf ^ 1);
        #pragma unroll
        for (int ks = 0; ks < 2; ks++) {
            bf16x8 af[8];
            #pragma unroll
            for (int mt = 0; mt < 8; mt++)
                af[mt] = expand8((unsigned int)(zw[mt] >> (ks * 32 + ko * 8)) & 0xFFu);
            #pragma unroll
            for (int nt = 0; nt < 4; nt++) {
                #pragma unroll
                for (int s = 0; s < 2; s++) {
                    bf16x8 bf = *(const bf16x8*)&Bs[buf][ks*8192 + (wn*4 + nt)*1024 + s*512 + lane*8];
                    #pragma unroll
                    for (int mt = 0; mt < 8; mt++)
                        acc[mt][nt] = __builtin_amdgcn_mfma_f32_16x16x32_bf16(af[mt], bf, acc[mt][nt], 0, 0, 0);
                }
            }
        }
        __syncthreads();
    }
    #pragma unroll
    for (int nt = 0; nt < 4; nt++) {
        const int o = bn * 128 + wn * 64 + nt * 16 + ln;
        const float bias = b2[o];
        #pragma unroll
        for (int mt = 0; mt < 8; mt++) {
            #pragma unroll
            for (int r = 0; r < 4; r++) {
                const int brow = b0 + mt * 16 + ko * 4 + r;
                a2[((size_t)t_l * BSZ + brow) * N2 + o] = acc[mt][nt][r] + bias;
            }
        }
    }
    #undef STAGE_B
}

// ============ LIF2 spikes only ============
__global__ __launch_bounds__(256) void lif2z_kernel(
        const float* __restrict__ a2, float* __restrict__ v2s, float* __restrict__ i2s,
        unsigned long long* __restrict__ z2bits, int c) {
    const int b = blockIdx.x;
    const int n = threadIdx.x;
    const int wid = n >> 6, lane = n & 63;
    float v2, i2;
    if (c == 0) { v2 = 0.f; i2 = 0.f; }
    else { v2 = v2s[(size_t)b * N2 + n]; i2 = i2s[(size_t)b * N2 + n]; }
    for (int tl = 0; tl < CH; tl++) {
        float a = a2[((size_t)tl * BSZ + b) * N2 + n];
        float vd = v2 + DVM * (i2 - v2);
        bool z = (vd - VTH) > 0.f;
        unsigned long long m = __ballot(z);
        if (lane == 0) z2bits[((size_t)(c * CH + tl) * BSZ + b) * 4 + wid] = m;
        v2 = z ? 0.f : vd;
        i2 = DIS * i2 + a;
    }
    v2s[(size_t)b * N2 + n] = v2;
    i2s[(size_t)b * N2 + n] = i2;
}

// ============ GEMM3: a3 = z2 @ W3.T + b3 (bit-dot) ============
__global__ __launch_bounds__(256) void gemm3_kernel(
        const unsigned long long* __restrict__ z2bits, const float* __restrict__ W3,
        const float* __restrict__ b3, float* __restrict__ a3) {
    const int idx = blockIdx.x * 256 + threadIdx.x;
    unsigned long long zw[4];
    #pragma unroll
    for (int g = 0; g < 4; g++) zw[g] = z2bits[(size_t)idx * 4 + g];
    float acc[NO];
    #pragma unroll
    for (int o = 0; o < NO; o++) acc[o] = b3[o];
    #pragma unroll
    for (int g = 0; g < 4; g++) {
        unsigned long long wg = zw[g];
        for (int kb = 0; kb < 64; kb++) {
            float bit = (float)((wg >> kb) & 1ull);
            #pragma unroll
            for (int o = 0; o < NO; o++)
                acc[o] = fmaf(bit, W3[o * N2 + g * 64 + kb], acc[o]);
        }
    }
    #pragma unroll
    for (int o = 0; o < NO; o++) a3[(size_t)idx * NO + o] = acc[o];
}

// ============ LI + max over time ============
__global__ __launch_bounds__(256) void li_kernel(
        const float* __restrict__ a3, const float* __restrict__ noise,
        float* __restrict__ out) {
    const int idx = blockIdx.x * 256 + threadIdx.x;
    if (idx >= BSZ * NO) return;
    float vl = 0.f, il = 0.f, mx = -1e30f;
    for (int t = 0; t < SEQ; t++) {
        float a = a3[(size_t)t * (BSZ * NO) + idx];
        float vn = vl + DVM * (il - vl);
        il = DIS * il + a;
        vl = vn;
        mx = fmaxf(mx, vl + 0.001f * noise[(size_t)t * (BSZ * NO) + idx]);
    }
    out[idx] = mx;
}

// ---------------- host ----------------
extern "C" void kernel_launch(void* const* d_in, const int* in_sizes, int n_in,
                              void* d_out, int out_size, void* d_ws, size_t ws_size,
                              hipStream_t stream) {
    const float* x     = (const float*)d_in[0];
    const float* W1    = (const float*)d_in[1];
    const float* b1    = (const float*)d_in[2];
    const float* W2    = (const float*)d_in[3];
    const float* b2    = (const float*)d_in[4];
    const float* W3    = (const float*)d_in[5];
    const float* b3    = (const float*)d_in[6];
    const float* noise = (const float*)d_in[7];
    float* out = (float*)d_out;

    char* ws = (char*)d_ws;
    float* inp1 = (float*)(ws + OFF_INP1);
    float* a2   = (float*)(ws + OFF_A2);
    float* a3   = (float*)(ws + OFF_A3);
    unsigned short* xf  = (unsigned short*)(ws + OFF_XF);
    unsigned short* w1f = (unsigned short*)(ws + OFF_W1F);
    unsigned long long* z1 = (unsigned long long*)(ws + OFF_Z1);
    float* v2 = (float*)(ws + OFF_V2);
    float* i2 = (float*)(ws + OFF_I2);
    unsigned long long* z2 = (unsigned long long*)(ws + OFF_Z2);
    unsigned short* w2f = (unsigned short*)(ws + OFF_W2F);

    dim3 blk(256);
    prep_x_kernel<<<dim3(6144), blk, 0, stream>>>(x, xf);
    prep_w1_kernel<<<dim3(2304), blk, 0, stream>>>(W1, w1f);
    prep_w2_kernel<<<dim3(192), blk, 0, stream>>>(W2, w2f);
    gemm1_mfma<<<dim3(384), blk, 0, stream>>>(xf, w1f, b1, inp1);
    lif1_kernel<<<dim3(N1/256, BSZ), blk, 0, stream>>>(inp1, z1);   // z1 overlays xf (dead)
    for (int c = 0; c < NCHUNK; c++) {
        gemm2_mfma<<<dim3(256, 2), blk, 0, stream>>>(z1, w2f, b2, a2, c);
        lif2z_kernel<<<dim3(BSZ), blk, 0, stream>>>(a2, v2, i2, z2, c);  // v2/i2/z2 overlay w1f (dead)
    }
    gemm3_kernel<<<dim3(SEQ * BSZ / 256), blk, 0, stream>>>(z2, W3, b3, a3);
    li_kernel<<<dim3((BSZ * NO + 255) / 256), blk, 0, stream>>>(a3, noise, out);
}

// Round 9
// 1237.893 us; speedup vs baseline: 1.1646x; 1.1646x over previous
//
#include <hip/hip_runtime.h>

// ---------------- problem constants ----------------
#define BSZ   4096
#define NIN   3072
#define N1    1536
#define N2    256
#define NO    10
#define SEQ   128
#define CH    16            // timesteps per chunk
#define NCHUNK (SEQ/CH)

// dynamics constants
#define DVM  0.1f           // DT*TAU_MEM_INV
#define DIS  0.8f           // 1 - DT*TAU_SYN_INV
#define VTH  0.4f

// ---------------- workspace layout (bytes) ----------------
// [0, 67108864)        : inp1 (25MB) -> a2 (67MB per chunk) -> a3 (21MB)
// [67108864, ...)      : xfrag (75.5MB, dead after gemm1)  UNION  z1d (100.7MB)
// [167772160, ...)     : w1frag (28.3MB, dead after gemm1) UNION  v2+i2+z2 (25.2MB)
// [196083712, ...)     : w2frag 3.1MB ; end 199229440
#define OFF_INP1 0
#define OFF_A2   0
#define OFF_A3   0
#define OFF_XF   67108864
#define OFF_Z1   67108864
#define OFF_W1F  167772160
#define OFF_V2   167772160
#define OFF_I2   171966464
#define OFF_Z2   176160768
#define OFF_W2F  196083712

typedef short bf16x8 __attribute__((ext_vector_type(8)));
typedef float f32x4  __attribute__((ext_vector_type(4)));

__device__ __forceinline__ void gload_lds16(const unsigned short* g, unsigned short* l) {
    __builtin_amdgcn_global_load_lds(
        (const __attribute__((address_space(1))) unsigned int*)g,
        (__attribute__((address_space(3))) unsigned int*)l, 16, 0, 0);
}

__device__ __forceinline__ unsigned short rne_bf16(float x) {
    unsigned u = __float_as_uint(x);
    return (unsigned short)((u + 0x7FFFu + ((u >> 16) & 1u)) >> 16);
}
__device__ __forceinline__ float bf2f(unsigned short h) {
    return __uint_as_float(((unsigned)h) << 16);
}

// ============ prep_x: 3-digit bf16 split of x, MFMA-fragment order ============
__global__ __launch_bounds__(256) void prep_x_kernel(
        const float* __restrict__ x, unsigned short* __restrict__ xf) {
    const int idx = blockIdx.x * 256 + threadIdx.x;
    const int lane = idx & 63;
    const int m16 = (idx >> 6) & 255;
    const int ks  = idx >> 14;                 // 0..95
    const int row = m16 * 16 + (lane & 15);
    const int k0  = ks * 32 + (lane >> 4) * 8;
    const float* src = x + (size_t)row * NIN + k0;
    union { unsigned short u[8]; bf16x8 v; } h, m, l;
    #pragma unroll
    for (int j = 0; j < 8; j++) {
        float v = src[j];
        h.u[j] = rne_bf16(v);
        float r1 = v - bf2f(h.u[j]);
        m.u[j] = rne_bf16(r1);
        float r2 = r1 - bf2f(m.u[j]);
        l.u[j] = rne_bf16(r2);
    }
    unsigned short* dst = xf + ((size_t)(ks * 256 + m16) * 3) * 512 + lane * 8;
    *(bf16x8*)(dst)        = h.v;
    *(bf16x8*)(dst + 512)  = m.v;
    *(bf16x8*)(dst + 1024) = l.v;
}

// ============ prep_w1: 3-digit split of W1, fragment order for LDS staging ============
__global__ __launch_bounds__(256) void prep_w1_kernel(
        const float* __restrict__ W1, unsigned short* __restrict__ wf) {
    const int idx = blockIdx.x * 256 + threadIdx.x;
    const int ks  = idx / 6144;                // 0..95
    const int rem = idx % 6144;
    const int n16 = rem >> 6;                  // 0..95
    const int lane = rem & 63;
    const int row = n16 * 16 + (lane & 15);
    const int k0  = ks * 32 + (lane >> 4) * 8;
    const float* src = W1 + (size_t)row * NIN + k0;
    union { unsigned short u[8]; bf16x8 v; } h, m, l;
    #pragma unroll
    for (int j = 0; j < 8; j++) {
        float v = src[j];
        h.u[j] = rne_bf16(v);
        float r1 = v - bf2f(h.u[j]);
        m.u[j] = rne_bf16(r1);
        float r2 = r1 - bf2f(m.u[j]);
        l.u[j] = rne_bf16(r2);
    }
    unsigned short* dst = wf + ((size_t)ks * 12 + (n16 >> 3)) * 12288
                             + (n16 & 7) * 1536 + lane * 8;
    *(bf16x8*)(dst)        = h.v;
    *(bf16x8*)(dst + 512)  = m.v;
    *(bf16x8*)(dst + 1024) = l.v;
}

// ============ GEMM1 via MFMA: inp1 = x @ W1.T + b1, 6-product digit split ============
__global__ __launch_bounds__(256, 2) void gemm1_mfma(
        const unsigned short* __restrict__ xf, const unsigned short* __restrict__ w1f,
        const float* __restrict__ b1, float* __restrict__ inp1) {
    __shared__ unsigned short Bs[2][12288];    // 2 x 24 KB
    const int tx = threadIdx.x;
    const int wave = tx >> 6, lane = tx & 63;
    const int wm = wave >> 1, wn = wave & 1;
    const int ln = lane & 15, ko = lane >> 4;
    const int bid = blockIdx.x;                // 384 blocks
    const int wg = (bid & 7) * 48 + (bid >> 3);   // XCD-chunked swizzle (384%8==0)
    const int mtile = wg / 12, ntile = wg % 12;
    const int m16b = mtile * 8 + wm * 4;

    f32x4 acc[4][4];
    #pragma unroll
    for (int mt = 0; mt < 4; mt++)
        #pragma unroll
        for (int nt = 0; nt < 4; nt++) acc[mt][nt] = (f32x4){0.f,0.f,0.f,0.f};

    const unsigned short* xfr = xf + lane * 8;

#define ALOAD(A_, ks_) do {                                                   \
    _Pragma("unroll")                                                         \
    for (int mt_ = 0; mt_ < 4; mt_++)                                         \
        _Pragma("unroll")                                                     \
        for (int d_ = 0; d_ < 3; d_++)                                        \
            A_[mt_][d_] = *(const bf16x8*)(xfr +                              \
                (((size_t)(ks_) * 256 + m16b + mt_) * 3 + d_) * 512);         \
} while (0)

#define STAGE1(ks_, buf_) do {                                                \
    const unsigned short* s_ = w1f + ((size_t)(ks_) * 12 + ntile) * 12288     \
                                   + wave * 3072 + lane * 8;                  \
    unsigned short* d_ = &Bs[buf_][wave * 3072];                              \
    _Pragma("unroll")                                                         \
    for (int j_ = 0; j_ < 6; j_++)                                            \
        gload_lds16(s_ + j_ * 512, d_ + j_ * 512);                            \
} while (0)

#define COMPUTE(A_, buf_) do {                                                \
    _Pragma("unroll")                                                         \
    for (int nt_ = 0; nt_ < 4; nt_++) {                                       \
        const unsigned short* bp_ = &Bs[buf_][(wn * 4 + nt_) * 1536 + lane * 8]; \
        bf16x8 bh_ = *(const bf16x8*)(bp_);                                   \
        bf16x8 bm_ = *(const bf16x8*)(bp_ + 512);                             \
        bf16x8 bl_ = *(const bf16x8*)(bp_ + 1024);                            \
        _Pragma("unroll")                                                     \
        for (int mt_ = 0; mt_ < 4; mt_++) {                                   \
            acc[mt_][nt_] = __builtin_amdgcn_mfma_f32_16x16x32_bf16(A_[mt_][0], bh_, acc[mt_][nt_], 0, 0, 0); \
            acc[mt_][nt_] = __builtin_amdgcn_mfma_f32_16x16x32_bf16(A_[mt_][1], bh_, acc[mt_][nt_], 0, 0, 0); \
            acc[mt_][nt_] = __builtin_amdgcn_mfma_f32_16x16x32_bf16(A_[mt_][2], bh_, acc[mt_][nt_], 0, 0, 0); \
            acc[mt_][nt_] = __builtin_amdgcn_mfma_f32_16x16x32_bf16(A_[mt_][0], bm_, acc[mt_][nt_], 0, 0, 0); \
            acc[mt_][nt_] = __builtin_amdgcn_mfma_f32_16x16x32_bf16(A_[mt_][1], bm_, acc[mt_][nt_], 0, 0, 0); \
            acc[mt_][nt_] = __builtin_amdgcn_mfma_f32_16x16x32_bf16(A_[mt_][0], bl_, acc[mt_][nt_], 0, 0, 0); \
        }                                                                     \
    }                                                                         \
} while (0)

    bf16x8 aA[4][3], aB[4][3];
    ALOAD(aA, 0);
    STAGE1(0, 0);
    __syncthreads();

    for (int ks = 0; ks < 96; ks += 2) {
        STAGE1(ks + 1, 1);
        ALOAD(aB, ks + 1);
        COMPUTE(aA, 0);
        __syncthreads();
        if (ks + 2 < 96) {
            STAGE1(ks + 2, 0);
            ALOAD(aA, ks + 2);
        }
        COMPUTE(aB, 1);
        __syncthreads();
    }

    // epilogue: C/D col=lane&15, row=(lane>>4)*4+r
    #pragma unroll
    for (int nt = 0; nt < 4; nt++) {
        const int n = ntile * 128 + wn * 64 + nt * 16 + ln;
        const float bias = b1[n];
        #pragma unroll
        for (int mt = 0; mt < 4; mt++) {
            #pragma unroll
            for (int r = 0; r < 4; r++) {
                const int m = mtile * 128 + wm * 64 + mt * 16 + ko * 4 + r;
                inp1[(size_t)m * N1 + n] = acc[mt][nt][r] + bias;
            }
        }
    }
#undef ALOAD
#undef STAGE1
#undef COMPUTE
}

// ============ LIF1: ballot-free. Each thread accumulates its neuron's 128 spike
// bits (u=(u<<1)|z, MSB-first in time), then a 64x64 bit-matrix butterfly
// transpose across the wave + bit-reverse yields, per lane l, the word
// {bit k = spike of neuron w*64+k} at time t=l (and t=64+l).
// NEW layout z1d[bg][w][t][bl] (bg=b>>7, bl=b&127): batch-contiguous words so
// gemm2's A-loads are coalesced (the scatter happens here, once).
__global__ __launch_bounds__(256) void lif1_kernel(
        const float* __restrict__ inp1, unsigned long long* __restrict__ z1d) {
    const int b = blockIdx.y;
    const int n = blockIdx.x * 256 + threadIdx.x;
    const int lane = threadIdx.x & 63;
    const int w = n >> 6;                      // word index 0..23
    const float inp = inp1[(size_t)b * N1 + n];
    float v = 0.f, i = 0.f;
    unsigned int u[4];
    #pragma unroll
    for (int s = 0; s < 4; s++) {
        unsigned int acc = 0;
        #pragma unroll
        for (int k = 0; k < 32; k++) {
            float vd = v + DVM * (i - v);
            bool z = (vd - VTH) > 0.f;
            acc = (acc << 1) | (z ? 1u : 0u);
            v = z ? 0.f : vd;
            i = DIS * i + inp;
        }
        u[s] = acc;
    }
    // X bit p = z(63-p) (block0: t=0..63) / z(127-p) (block1) -> MSB-first columns
    unsigned long long X0 = ((unsigned long long)u[0] << 32) | u[1];
    unsigned long long X1 = ((unsigned long long)u[2] << 32) | u[3];
    // 64x64 bit transpose (Hacker's Delight form, lanes = rows)
    #pragma unroll
    for (int s = 0; s < 6; s++) {
        const int j = 32 >> s;
        const unsigned long long m =
            (s == 0) ? 0x00000000FFFFFFFFull :
            (s == 1) ? 0x0000FFFF0000FFFFull :
            (s == 2) ? 0x00FF00FF00FF00FFull :
            (s == 3) ? 0x0F0F0F0F0F0F0F0Full :
            (s == 4) ? 0x3333333333333333ull : 0x5555555555555555ull;
        unsigned long long p0 = __shfl_xor(X0, j, 64);
        unsigned long long p1 = __shfl_xor(X1, j, 64);
        if (lane & j) {
            X0 = (X0 & m) | ((p0 << j) & ~m);
            X1 = (X1 & m) | ((p1 << j) & ~m);
        } else {
            X0 = (X0 & ~m) | ((p0 >> j) & m);
            X1 = (X1 & ~m) | ((p1 >> j) & m);
        }
    }
    // now lane l holds time t=l with bit p = neuron (63-p); bit-reverse -> bit k = neuron k
    unsigned long long Y0 = ((unsigned long long)__builtin_bitreverse32((unsigned int)X0) << 32)
                          | __builtin_bitreverse32((unsigned int)(X0 >> 32));
    unsigned long long Y1 = ((unsigned long long)__builtin_bitreverse32((unsigned int)X1) << 32)
                          | __builtin_bitreverse32((unsigned int)(X1 >> 32));
    const int bg = b >> 7, bl = b & 127;
    unsigned long long* zb = z1d + ((size_t)(bg * 24 + w) * 128) * 128 + bl;
    zb[(size_t)lane * 128]        = Y0;        // t = lane
    zb[(size_t)(64 + lane) * 128] = Y1;        // t = 64 + lane
}

// ============ W2 prep: split hi/lo bf16 in MFMA fragment order ============
__global__ __launch_bounds__(256) void prep_w2_kernel(
        const float* __restrict__ W2, unsigned short* __restrict__ frag) {
    const int idx = blockIdx.x * 256 + threadIdx.x;
    const int lane = idx & 63;
    const int ntg  = (idx >> 6) & 15;
    const int ks   = (idx >> 10) & 1;
    const int w    = idx >> 11;
    const int n = ntg * 16 + (lane & 15);
    const int k = w * 64 + ks * 32 + (lane >> 4) * 8;
    const int nblk = ntg >> 3, nt8 = ntg & 7;
    const size_t base = ((size_t)(w * 2 + nblk)) * 16384 + ks * 8192 + nt8 * 1024 + lane * 8;
    const float* src = W2 + (size_t)n * N1 + k;
    #pragma unroll
    for (int j = 0; j < 8; j++) {
        float x = src[j];
        unsigned short h = rne_bf16(x);
        frag[base + j] = h;
        float r = x - bf2f(h);
        frag[base + 512 + j] = rne_bf16(r);
    }
}

// byte (8 spike bits) -> 8 bf16 {0.0, 1.0}
__device__ __forceinline__ bf16x8 expand8(unsigned int byte) {
    union { unsigned int u[4]; bf16x8 v; } r;
    #pragma unroll
    for (int p = 0; p < 4; p++) {
        unsigned int lo = ((byte >> (2*p)) & 1u) * 0x3F80u;
        unsigned int hi = ((byte >> (2*p+1)) & 1u) * 0x3F80u;
        r.u[p] = lo | (hi << 16);
    }
    return r.v;
}

// ============ GEMM2: a2 = z1 @ (W2hi+W2lo).T + b2 via MFMA ============
// z1d layout [bg][w][t][bl]: A-loads coalesced (16 consecutive 8B words / load).
__global__ __launch_bounds__(256, 2) void gemm2_mfma(
        const unsigned long long* __restrict__ z1d,
        const unsigned short* __restrict__ w2frag,
        const float* __restrict__ b2, float* __restrict__ a2, int c) {
    __shared__ unsigned short Bs[2][16384];
    const int tx = threadIdx.x;
    const int wave = tx >> 6, lane = tx & 63;
    const int wm = wave >> 1, wn = wave & 1;
    const int ko = lane >> 4, ln = lane & 15;
    const int bm = blockIdx.x;
    const int bn = blockIdx.y;
    const int t_l = bm >> 4;
    const int b0 = (bm & 15) * 256 + wm * 128;
    const int t  = c * CH + t_l;

    f32x4 acc[8][4];
    #pragma unroll
    for (int mt = 0; mt < 8; mt++)
        #pragma unroll
        for (int nt = 0; nt < 4; nt++) acc[mt][nt] = (f32x4){0.f,0.f,0.f,0.f};

    const int bg = b0 >> 7;                    // 128-row group
    // z1d word index: ((bg*24 + w)*128 + t)*128 + bl,  bl = ln + mt*16
    const size_t zbase2 = ((size_t)(bg * 24) * 128 + t) * 128 + ln;
    const unsigned short* sgbase = w2frag + (size_t)bn * 16384 + wave * 4096 + lane * 8;
    #define STAGE_B(w_, buf_) do {                                           \
        const unsigned short* s_ = sgbase + (size_t)(w_) * 32768;            \
        unsigned short* d_ = &Bs[buf_][wave * 4096];                         \
        _Pragma("unroll")                                                    \
        for (int j_ = 0; j_ < 8; j_++)                                       \
            gload_lds16(s_ + j_ * 512, d_ + j_ * 512);                       \
    } while (0)

    STAGE_B(0, 0);
    __syncthreads();

    for (int w = 0; w < 24; w++) {
        const int buf = w & 1;
        // zw loads first (coalesced in new layout)
        unsigned long long zw[8];
        #pragma unroll
        for (int mt = 0; mt < 8; mt++)
            zw[mt] = z1d[zbase2 + (size_t)w * 16384 + mt * 16];
        if (w < 23) STAGE_B(w + 1, buf ^ 1);
        #pragma unroll
        for (int ks = 0; ks < 2; ks++) {
            bf16x8 af[8];
            #pragma unroll
            for (int mt = 0; mt < 8; mt++)
                af[mt] = expand8((unsigned int)(zw[mt] >> (ks * 32 + ko * 8)) & 0xFFu);
            #pragma unroll
            for (int nt = 0; nt < 4; nt++) {
                #pragma unroll
                for (int s = 0; s < 2; s++) {
                    bf16x8 bf = *(const bf16x8*)&Bs[buf][ks*8192 + (wn*4 + nt)*1024 + s*512 + lane*8];
                    #pragma unroll
                    for (int mt = 0; mt < 8; mt++)
                        acc[mt][nt] = __builtin_amdgcn_mfma_f32_16x16x32_bf16(af[mt], bf, acc[mt][nt], 0, 0, 0);
                }
            }
        }
        __syncthreads();
    }
    #pragma unroll
    for (int nt = 0; nt < 4; nt++) {
        const int o = bn * 128 + wn * 64 + nt * 16 + ln;
        const float bias = b2[o];
        #pragma unroll
        for (int mt = 0; mt < 8; mt++) {
            #pragma unroll
            for (int r = 0; r < 4; r++) {
                const int brow = b0 + mt * 16 + ko * 4 + r;
                a2[((size_t)t_l * BSZ + brow) * N2 + o] = acc[mt][nt][r] + bias;
            }
        }
    }
    #undef STAGE_B
}

// ============ LIF2 spikes only ============
__global__ __launch_bounds__(256) void lif2z_kernel(
        const float* __restrict__ a2, float* __restrict__ v2s, float* __restrict__ i2s,
        unsigned long long* __restrict__ z2bits, int c) {
    const int b = blockIdx.x;
    const int n = threadIdx.x;
    const int wid = n >> 6, lane = n & 63;
    float v2, i2;
    if (c == 0) { v2 = 0.f; i2 = 0.f; }
    else { v2 = v2s[(size_t)b * N2 + n]; i2 = i2s[(size_t)b * N2 + n]; }
    for (int tl = 0; tl < CH; tl++) {
        float a = a2[((size_t)tl * BSZ + b) * N2 + n];
        float vd = v2 + DVM * (i2 - v2);
        bool z = (vd - VTH) > 0.f;
        unsigned long long m = __ballot(z);
        if (lane == 0) z2bits[((size_t)(c * CH + tl) * BSZ + b) * 4 + wid] = m;
        v2 = z ? 0.f : vd;
        i2 = DIS * i2 + a;
    }
    v2s[(size_t)b * N2 + n] = v2;
    i2s[(size_t)b * N2 + n] = i2;
}

// ============ GEMM3: a3 = z2 @ W3.T + b3 (bit-dot) ============
__global__ __launch_bounds__(256) void gemm3_kernel(
        const unsigned long long* __restrict__ z2bits, const float* __restrict__ W3,
        const float* __restrict__ b3, float* __restrict__ a3) {
    const int idx = blockIdx.x * 256 + threadIdx.x;
    unsigned long long zw[4];
    #pragma unroll
    for (int g = 0; g < 4; g++) zw[g] = z2bits[(size_t)idx * 4 + g];
    float acc[NO];
    #pragma unroll
    for (int o = 0; o < NO; o++) acc[o] = b3[o];
    #pragma unroll
    for (int g = 0; g < 4; g++) {
        unsigned long long wg = zw[g];
        for (int kb = 0; kb < 64; kb++) {
            float bit = (float)((wg >> kb) & 1ull);
            #pragma unroll
            for (int o = 0; o < NO; o++)
                acc[o] = fmaf(bit, W3[o * N2 + g * 64 + kb], acc[o]);
        }
    }
    #pragma unroll
    for (int o = 0; o < NO; o++) a3[(size_t)idx * NO + o] = acc[o];
}

// ============ LI + max over time ============
__global__ __launch_bounds__(256) void li_kernel(
        const float* __restrict__ a3, const float* __restrict__ noise,
        float* __restrict__ out) {
    const int idx = blockIdx.x * 256 + threadIdx.x;
    if (idx >= BSZ * NO) return;
    float vl = 0.f, il = 0.f, mx = -1e30f;
    for (int t = 0; t < SEQ; t++) {
        float a = a3[(size_t)t * (BSZ * NO) + idx];
        float vn = vl + DVM * (il - vl);
        il = DIS * il + a;
        vl = vn;
        mx = fmaxf(mx, vl + 0.001f * noise[(size_t)t * (BSZ * NO) + idx]);
    }
    out[idx] = mx;
}

// ---------------- host ----------------
extern "C" void kernel_launch(void* const* d_in, const int* in_sizes, int n_in,
                              void* d_out, int out_size, void* d_ws, size_t ws_size,
                              hipStream_t stream) {
    const float* x     = (const float*)d_in[0];
    const float* W1    = (const float*)d_in[1];
    const float* b1    = (const float*)d_in[2];
    const float* W2    = (const float*)d_in[3];
    const float* b2    = (const float*)d_in[4];
    const float* W3    = (const float*)d_in[5];
    const float* b3    = (const float*)d_in[6];
    const float* noise = (const float*)d_in[7];
    float* out = (float*)d_out;

    char* ws = (char*)d_ws;
    float* inp1 = (float*)(ws + OFF_INP1);
    float* a2   = (float*)(ws + OFF_A2);
    float* a3   = (float*)(ws + OFF_A3);
    unsigned short* xf  = (unsigned short*)(ws + OFF_XF);
    unsigned short* w1f = (unsigned short*)(ws + OFF_W1F);
    unsigned long long* z1 = (unsigned long long*)(ws + OFF_Z1);
    float* v2 = (float*)(ws + OFF_V2);
    float* i2 = (float*)(ws + OFF_I2);
    unsigned long long* z2 = (unsigned long long*)(ws + OFF_Z2);
    unsigned short* w2f = (unsigned short*)(ws + OFF_W2F);

    dim3 blk(256);
    prep_x_kernel<<<dim3(6144), blk, 0, stream>>>(x, xf);
    prep_w1_kernel<<<dim3(2304), blk, 0, stream>>>(W1, w1f);
    prep_w2_kernel<<<dim3(192), blk, 0, stream>>>(W2, w2f);
    gemm1_mfma<<<dim3(384), blk, 0, stream>>>(xf, w1f, b1, inp1);
    lif1_kernel<<<dim3(N1/256, BSZ), blk, 0, stream>>>(inp1, z1);   // z1 overlays xf (dead)
    for (int c = 0; c < NCHUNK; c++) {
        gemm2_mfma<<<dim3(256, 2), blk, 0, stream>>>(z1, w2f, b2, a2, c);
        lif2z_kernel<<<dim3(BSZ), blk, 0, stream>>>(a2, v2, i2, z2, c);  // v2/i2/z2 overlay w1f (dead)
    }
    gemm3_kernel<<<dim3(SEQ * BSZ / 256), blk, 0, stream>>>(z2, W3, b3, a3);
    li_kernel<<<dim3((BSZ * NO + 255) / 256), blk, 0, stream>>>(a3, noise, out);
}

// Round 10
// 1216.038 us; speedup vs baseline: 1.1855x; 1.0180x over previous
//
#include <hip/hip_runtime.h>

// ---------------- problem constants ----------------
#define BSZ   4096
#define NIN   3072
#define N1    1536
#define N2    256
#define NO    10
#define SEQ   128
#define CH    16            // timesteps per chunk
#define NCHUNK (SEQ/CH)

// dynamics constants
#define DVM  0.1f           // DT*TAU_MEM_INV
#define DIS  0.8f           // 1 - DT*TAU_SYN_INV
#define VTH  0.4f

// ---------------- workspace layout (bytes) ----------------
// [0, 67108864)        : inp1 (25MB) -> a2 (67MB per chunk) -> a3 (21MB)
// [67108864, ...)      : xfrag (75.5MB, dead after gemm1)  UNION  z1d (100.7MB)
// [167772160, ...)     : w1frag (28.3MB, dead after gemm1) UNION  v2+i2+z2 (25.2MB)
// [196083712, ...)     : w2frag 3.1MB ; end 199229440
#define OFF_INP1 0
#define OFF_A2   0
#define OFF_A3   0
#define OFF_XF   67108864
#define OFF_Z1   67108864
#define OFF_W1F  167772160
#define OFF_V2   167772160
#define OFF_I2   171966464
#define OFF_Z2   176160768
#define OFF_W2F  196083712

typedef short bf16x8 __attribute__((ext_vector_type(8)));
typedef float f32x4  __attribute__((ext_vector_type(4)));

__device__ __forceinline__ void gload_lds16(const unsigned short* g, unsigned short* l) {
    __builtin_amdgcn_global_load_lds(
        (const __attribute__((address_space(1))) unsigned int*)g,
        (__attribute__((address_space(3))) unsigned int*)l, 16, 0, 0);
}

__device__ __forceinline__ unsigned short rne_bf16(float x) {
    unsigned u = __float_as_uint(x);
    return (unsigned short)((u + 0x7FFFu + ((u >> 16) & 1u)) >> 16);
}
__device__ __forceinline__ float bf2f(unsigned short h) {
    return __uint_as_float(((unsigned)h) << 16);
}

// ============ prep_x: 3-digit bf16 split of x, MFMA-fragment order ============
__global__ __launch_bounds__(256) void prep_x_kernel(
        const float* __restrict__ x, unsigned short* __restrict__ xf) {
    const int idx = blockIdx.x * 256 + threadIdx.x;
    const int lane = idx & 63;
    const int m16 = (idx >> 6) & 255;
    const int ks  = idx >> 14;                 // 0..95
    const int row = m16 * 16 + (lane & 15);
    const int k0  = ks * 32 + (lane >> 4) * 8;
    const float* src = x + (size_t)row * NIN + k0;
    union { unsigned short u[8]; bf16x8 v; } h, m, l;
    #pragma unroll
    for (int j = 0; j < 8; j++) {
        float v = src[j];
        h.u[j] = rne_bf16(v);
        float r1 = v - bf2f(h.u[j]);
        m.u[j] = rne_bf16(r1);
        float r2 = r1 - bf2f(m.u[j]);
        l.u[j] = rne_bf16(r2);
    }
    unsigned short* dst = xf + ((size_t)(ks * 256 + m16) * 3) * 512 + lane * 8;
    *(bf16x8*)(dst)        = h.v;
    *(bf16x8*)(dst + 512)  = m.v;
    *(bf16x8*)(dst + 1024) = l.v;
}

// ============ prep_w1: 3-digit split of W1, fragment order for LDS staging ============
__global__ __launch_bounds__(256) void prep_w1_kernel(
        const float* __restrict__ W1, unsigned short* __restrict__ wf) {
    const int idx = blockIdx.x * 256 + threadIdx.x;
    const int ks  = idx / 6144;                // 0..95
    const int rem = idx % 6144;
    const int n16 = rem >> 6;                  // 0..95
    const int lane = rem & 63;
    const int row = n16 * 16 + (lane & 15);
    const int k0  = ks * 32 + (lane >> 4) * 8;
    const float* src = W1 + (size_t)row * NIN + k0;
    union { unsigned short u[8]; bf16x8 v; } h, m, l;
    #pragma unroll
    for (int j = 0; j < 8; j++) {
        float v = src[j];
        h.u[j] = rne_bf16(v);
        float r1 = v - bf2f(h.u[j]);
        m.u[j] = rne_bf16(r1);
        float r2 = r1 - bf2f(m.u[j]);
        l.u[j] = rne_bf16(r2);
    }
    unsigned short* dst = wf + ((size_t)ks * 12 + (n16 >> 3)) * 12288
                             + (n16 & 7) * 1536 + lane * 8;
    *(bf16x8*)(dst)        = h.v;
    *(bf16x8*)(dst + 512)  = m.v;
    *(bf16x8*)(dst + 1024) = l.v;
}

// ============ GEMM1 via MFMA: inp1 = x @ W1.T + b1, 6-product digit split ============
// RETILED 64M x 128N: grid 768 = exactly 3 blocks/CU (was 384 = 1.5, half CUs idle).
// Only M-side indexing changed vs 128x128 version; w1f layout/STAGE identical.
__global__ __launch_bounds__(256, 3) void gemm1_mfma(
        const unsigned short* __restrict__ xf, const unsigned short* __restrict__ w1f,
        const float* __restrict__ b1, float* __restrict__ inp1) {
    __shared__ unsigned short Bs[2][12288];    // 2 x 24 KB
    const int tx = threadIdx.x;
    const int wave = tx >> 6, lane = tx & 63;
    const int wm = wave >> 1, wn = wave & 1;
    const int ln = lane & 15, ko = lane >> 4;
    const int bid = blockIdx.x;                // 768 blocks
    const int wg = (bid & 7) * 96 + (bid >> 3);   // XCD-chunked swizzle (768%8==0)
    const int mtile = wg / 12, ntile = wg % 12;   // mtile 0..63
    const int m16b = mtile * 4 + wm * 2;

    f32x4 acc[2][4];
    #pragma unroll
    for (int mt = 0; mt < 2; mt++)
        #pragma unroll
        for (int nt = 0; nt < 4; nt++) acc[mt][nt] = (f32x4){0.f,0.f,0.f,0.f};

    const unsigned short* xfr = xf + lane * 8;

#define ALOAD(A_, ks_) do {                                                   \
    _Pragma("unroll")                                                         \
    for (int mt_ = 0; mt_ < 2; mt_++)                                         \
        _Pragma("unroll")                                                     \
        for (int d_ = 0; d_ < 3; d_++)                                        \
            A_[mt_][d_] = *(const bf16x8*)(xfr +                              \
                (((size_t)(ks_) * 256 + m16b + mt_) * 3 + d_) * 512);         \
} while (0)

#define STAGE1(ks_, buf_) do {                                                \
    const unsigned short* s_ = w1f + ((size_t)(ks_) * 12 + ntile) * 12288     \
                                   + wave * 3072 + lane * 8;                  \
    unsigned short* d_ = &Bs[buf_][wave * 3072];                              \
    _Pragma("unroll")                                                         \
    for (int j_ = 0; j_ < 6; j_++)                                            \
        gload_lds16(s_ + j_ * 512, d_ + j_ * 512);                            \
} while (0)

#define COMPUTE(A_, buf_) do {                                                \
    _Pragma("unroll")                                                         \
    for (int nt_ = 0; nt_ < 4; nt_++) {                                       \
        const unsigned short* bp_ = &Bs[buf_][(wn * 4 + nt_) * 1536 + lane * 8]; \
        bf16x8 bh_ = *(const bf16x8*)(bp_);                                   \
        bf16x8 bm_ = *(const bf16x8*)(bp_ + 512);                             \
        bf16x8 bl_ = *(const bf16x8*)(bp_ + 1024);                            \
        _Pragma("unroll")                                                     \
        for (int mt_ = 0; mt_ < 2; mt_++) {                                   \
            acc[mt_][nt_] = __builtin_amdgcn_mfma_f32_16x16x32_bf16(A_[mt_][0], bh_, acc[mt_][nt_], 0, 0, 0); \
            acc[mt_][nt_] = __builtin_amdgcn_mfma_f32_16x16x32_bf16(A_[mt_][1], bh_, acc[mt_][nt_], 0, 0, 0); \
            acc[mt_][nt_] = __builtin_amdgcn_mfma_f32_16x16x32_bf16(A_[mt_][2], bh_, acc[mt_][nt_], 0, 0, 0); \
            acc[mt_][nt_] = __builtin_amdgcn_mfma_f32_16x16x32_bf16(A_[mt_][0], bm_, acc[mt_][nt_], 0, 0, 0); \
            acc[mt_][nt_] = __builtin_amdgcn_mfma_f32_16x16x32_bf16(A_[mt_][1], bm_, acc[mt_][nt_], 0, 0, 0); \
            acc[mt_][nt_] = __builtin_amdgcn_mfma_f32_16x16x32_bf16(A_[mt_][0], bl_, acc[mt_][nt_], 0, 0, 0); \
        }                                                                     \
    }                                                                         \
} while (0)

    bf16x8 aA[2][3], aB[2][3];
    ALOAD(aA, 0);
    STAGE1(0, 0);
    __syncthreads();

    for (int ks = 0; ks < 96; ks += 2) {
        STAGE1(ks + 1, 1);
        ALOAD(aB, ks + 1);
        COMPUTE(aA, 0);
        __syncthreads();
        if (ks + 2 < 96) {
            STAGE1(ks + 2, 0);
            ALOAD(aA, ks + 2);
        }
        COMPUTE(aB, 1);
        __syncthreads();
    }

    // epilogue: C/D col=lane&15, row=(lane>>4)*4+r
    #pragma unroll
    for (int nt = 0; nt < 4; nt++) {
        const int n = ntile * 128 + wn * 64 + nt * 16 + ln;
        const float bias = b1[n];
        #pragma unroll
        for (int mt = 0; mt < 2; mt++) {
            #pragma unroll
            for (int r = 0; r < 4; r++) {
                const int m = mtile * 64 + wm * 32 + mt * 16 + ko * 4 + r;
                inp1[(size_t)m * N1 + n] = acc[mt][nt][r] + bias;
            }
        }
    }
#undef ALOAD
#undef STAGE1
#undef COMPUTE
}

// ============ LIF1: ballot-free; per-thread bit accumulate + 64x64 wave bit-transpose
// layout z1d[bg][w][t][bl] (bg=b>>7, bl=b&127): batch-contiguous words so gemm2's
// A-loads are coalesced.
__global__ __launch_bounds__(256) void lif1_kernel(
        const float* __restrict__ inp1, unsigned long long* __restrict__ z1d) {
    const int b = blockIdx.y;
    const int n = blockIdx.x * 256 + threadIdx.x;
    const int lane = threadIdx.x & 63;
    const int w = n >> 6;                      // word index 0..23
    const float inp = inp1[(size_t)b * N1 + n];
    float v = 0.f, i = 0.f;
    unsigned int u[4];
    #pragma unroll
    for (int s = 0; s < 4; s++) {
        unsigned int acc = 0;
        #pragma unroll
        for (int k = 0; k < 32; k++) {
            float vd = v + DVM * (i - v);
            bool z = (vd - VTH) > 0.f;
            acc = (acc << 1) | (z ? 1u : 0u);
            v = z ? 0.f : vd;
            i = DIS * i + inp;
        }
        u[s] = acc;
    }
    unsigned long long X0 = ((unsigned long long)u[0] << 32) | u[1];
    unsigned long long X1 = ((unsigned long long)u[2] << 32) | u[3];
    #pragma unroll
    for (int s = 0; s < 6; s++) {
        const int j = 32 >> s;
        const unsigned long long m =
            (s == 0) ? 0x00000000FFFFFFFFull :
            (s == 1) ? 0x0000FFFF0000FFFFull :
            (s == 2) ? 0x00FF00FF00FF00FFull :
            (s == 3) ? 0x0F0F0F0F0F0F0F0Full :
            (s == 4) ? 0x3333333333333333ull : 0x5555555555555555ull;
        unsigned long long p0 = __shfl_xor(X0, j, 64);
        unsigned long long p1 = __shfl_xor(X1, j, 64);
        if (lane & j) {
            X0 = (X0 & m) | ((p0 << j) & ~m);
            X1 = (X1 & m) | ((p1 << j) & ~m);
        } else {
            X0 = (X0 & ~m) | ((p0 >> j) & m);
            X1 = (X1 & ~m) | ((p1 >> j) & m);
        }
    }
    unsigned long long Y0 = ((unsigned long long)__builtin_bitreverse32((unsigned int)X0) << 32)
                          | __builtin_bitreverse32((unsigned int)(X0 >> 32));
    unsigned long long Y1 = ((unsigned long long)__builtin_bitreverse32((unsigned int)X1) << 32)
                          | __builtin_bitreverse32((unsigned int)(X1 >> 32));
    const int bg = b >> 7, bl = b & 127;
    unsigned long long* zb = z1d + ((size_t)(bg * 24 + w) * 128) * 128 + bl;
    zb[(size_t)lane * 128]        = Y0;        // t = lane
    zb[(size_t)(64 + lane) * 128] = Y1;        // t = 64 + lane
}

// ============ W2 prep: split hi/lo bf16 in MFMA fragment order ============
__global__ __launch_bounds__(256) void prep_w2_kernel(
        const float* __restrict__ W2, unsigned short* __restrict__ frag) {
    const int idx = blockIdx.x * 256 + threadIdx.x;
    const int lane = idx & 63;
    const int ntg  = (idx >> 6) & 15;
    const int ks   = (idx >> 10) & 1;
    const int w    = idx >> 11;
    const int n = ntg * 16 + (lane & 15);
    const int k = w * 64 + ks * 32 + (lane >> 4) * 8;
    const int nblk = ntg >> 3, nt8 = ntg & 7;
    const size_t base = ((size_t)(w * 2 + nblk)) * 16384 + ks * 8192 + nt8 * 1024 + lane * 8;
    const float* src = W2 + (size_t)n * N1 + k;
    #pragma unroll
    for (int j = 0; j < 8; j++) {
        float x = src[j];
        unsigned short h = rne_bf16(x);
        frag[base + j] = h;
        float r = x - bf2f(h);
        frag[base + 512 + j] = rne_bf16(r);
    }
}

// byte (8 spike bits) -> 8 bf16 {0.0, 1.0}
__device__ __forceinline__ bf16x8 expand8(unsigned int byte) {
    union { unsigned int u[4]; bf16x8 v; } r;
    #pragma unroll
    for (int p = 0; p < 4; p++) {
        unsigned int lo = ((byte >> (2*p)) & 1u) * 0x3F80u;
        unsigned int hi = ((byte >> (2*p+1)) & 1u) * 0x3F80u;
        r.u[p] = lo | (hi << 16);
    }
    return r.v;
}

// ============ GEMM2: a2 = z1 @ (W2hi+W2lo).T + b2 via MFMA ============
// z1d layout [bg][w][t][bl]: coalesced A-loads. zw register-double-buffered
// (2x unrolled w loop, static indexing) so spike-word latency hides under MFMA.
__global__ __launch_bounds__(256, 2) void gemm2_mfma(
        const unsigned long long* __restrict__ z1d,
        const unsigned short* __restrict__ w2frag,
        const float* __restrict__ b2, float* __restrict__ a2, int c) {
    __shared__ unsigned short Bs[2][16384];
    const int tx = threadIdx.x;
    const int wave = tx >> 6, lane = tx & 63;
    const int wm = wave >> 1, wn = wave & 1;
    const int ko = lane >> 4, ln = lane & 15;
    const int bm = blockIdx.x;
    const int bn = blockIdx.y;
    const int t_l = bm >> 4;
    const int b0 = (bm & 15) * 256 + wm * 128;
    const int t  = c * CH + t_l;

    f32x4 acc[8][4];
    #pragma unroll
    for (int mt = 0; mt < 8; mt++)
        #pragma unroll
        for (int nt = 0; nt < 4; nt++) acc[mt][nt] = (f32x4){0.f,0.f,0.f,0.f};

    const int bg = b0 >> 7;
    const size_t zbase2 = ((size_t)(bg * 24) * 128 + t) * 128 + ln;
    const unsigned short* sgbase = w2frag + (size_t)bn * 16384 + wave * 4096 + lane * 8;

    #define STAGE_B(w_, buf_) do {                                           \
        const unsigned short* s_ = sgbase + (size_t)(w_) * 32768;            \
        unsigned short* d_ = &Bs[buf_][wave * 4096];                         \
        _Pragma("unroll")                                                    \
        for (int j_ = 0; j_ < 8; j_++)                                       \
            gload_lds16(s_ + j_ * 512, d_ + j_ * 512);                       \
    } while (0)

    #define LOADZ(Z_, w_) do {                                               \
        _Pragma("unroll")                                                    \
        for (int mt_ = 0; mt_ < 8; mt_++)                                    \
            Z_[mt_] = z1d[zbase2 + (size_t)(w_) * 16384 + mt_ * 16];         \
    } while (0)

    #define COMP(Z_, buf_) do {                                              \
        _Pragma("unroll")                                                    \
        for (int ks = 0; ks < 2; ks++) {                                     \
            bf16x8 af[8];                                                    \
            _Pragma("unroll")                                                \
            for (int mt_ = 0; mt_ < 8; mt_++)                                \
                af[mt_] = expand8((unsigned int)(Z_[mt_] >> (ks * 32 + ko * 8)) & 0xFFu); \
            _Pragma("unroll")                                                \
            for (int nt_ = 0; nt_ < 4; nt_++) {                              \
                _Pragma("unroll")                                            \
                for (int s_ = 0; s_ < 2; s_++) {                             \
                    bf16x8 bf = *(const bf16x8*)&Bs[buf_][ks*8192 + (wn*4 + nt_)*1024 + s_*512 + lane*8]; \
                    _Pragma("unroll")                                        \
                    for (int mt_ = 0; mt_ < 8; mt_++)                        \
                        acc[mt_][nt_] = __builtin_amdgcn_mfma_f32_16x16x32_bf16(af[mt_], bf, acc[mt_][nt_], 0, 0, 0); \
                }                                                            \
            }                                                                \
        }                                                                    \
    } while (0)

    unsigned long long zwA[8], zwB[8];
    LOADZ(zwA, 0);
    STAGE_B(0, 0);
    __syncthreads();

    for (int w = 0; w < 24; w += 2) {
        // even step: prefetch w+1, compute w from zwA/buf0
        LOADZ(zwB, w + 1);
        STAGE_B(w + 1, 1);
        COMP(zwA, 0);
        __syncthreads();
        // odd step: prefetch w+2, compute w+1 from zwB/buf1
        if (w + 2 < 24) {
            LOADZ(zwA, w + 2);
            STAGE_B(w + 2, 0);
        }
        COMP(zwB, 1);
        __syncthreads();
    }

    #pragma unroll
    for (int nt = 0; nt < 4; nt++) {
        const int o = bn * 128 + wn * 64 + nt * 16 + ln;
        const float bias = b2[o];
        #pragma unroll
        for (int mt = 0; mt < 8; mt++) {
            #pragma unroll
            for (int r = 0; r < 4; r++) {
                const int brow = b0 + mt * 16 + ko * 4 + r;
                a2[((size_t)t_l * BSZ + brow) * N2 + o] = acc[mt][nt][r] + bias;
            }
        }
    }
    #undef STAGE_B
    #undef LOADZ
    #undef COMP
}

// ============ LIF2 spikes only (a2 prefetched: 16 independent loads up front) ============
__global__ __launch_bounds__(256) void lif2z_kernel(
        const float* __restrict__ a2, float* __restrict__ v2s, float* __restrict__ i2s,
        unsigned long long* __restrict__ z2bits, int c) {
    const int b = blockIdx.x;
    const int n = threadIdx.x;
    const int wid = n >> 6, lane = n & 63;
    float av[CH];
    #pragma unroll
    for (int tl = 0; tl < CH; tl++)
        av[tl] = a2[((size_t)tl * BSZ + b) * N2 + n];
    float v2, i2;
    if (c == 0) { v2 = 0.f; i2 = 0.f; }
    else { v2 = v2s[(size_t)b * N2 + n]; i2 = i2s[(size_t)b * N2 + n]; }
    #pragma unroll
    for (int tl = 0; tl < CH; tl++) {
        float vd = v2 + DVM * (i2 - v2);
        bool z = (vd - VTH) > 0.f;
        unsigned long long m = __ballot(z);
        if (lane == 0) z2bits[((size_t)(c * CH + tl) * BSZ + b) * 4 + wid] = m;
        v2 = z ? 0.f : vd;
        i2 = DIS * i2 + av[tl];
    }
    v2s[(size_t)b * N2 + n] = v2;
    i2s[(size_t)b * N2 + n] = i2;
}

// ============ GEMM3: a3 = z2 @ W3.T + b3 (bit-dot) ============
__global__ __launch_bounds__(256) void gemm3_kernel(
        const unsigned long long* __restrict__ z2bits, const float* __restrict__ W3,
        const float* __restrict__ b3, float* __restrict__ a3) {
    const int idx = blockIdx.x * 256 + threadIdx.x;
    unsigned long long zw[4];
    #pragma unroll
    for (int g = 0; g < 4; g++) zw[g] = z2bits[(size_t)idx * 4 + g];
    float acc[NO];
    #pragma unroll
    for (int o = 0; o < NO; o++) acc[o] = b3[o];
    #pragma unroll
    for (int g = 0; g < 4; g++) {
        unsigned long long wg = zw[g];
        for (int kb = 0; kb < 64; kb++) {
            float bit = (float)((wg >> kb) & 1ull);
            #pragma unroll
            for (int o = 0; o < NO; o++)
                acc[o] = fmaf(bit, W3[o * N2 + g * 64 + kb], acc[o]);
        }
    }
    #pragma unroll
    for (int o = 0; o < NO; o++) a3[(size_t)idx * NO + o] = acc[o];
}

// ============ LI + max over time ============
__global__ __launch_bounds__(256) void li_kernel(
        const float* __restrict__ a3, const float* __restrict__ noise,
        float* __restrict__ out) {
    const int idx = blockIdx.x * 256 + threadIdx.x;
    if (idx >= BSZ * NO) return;
    float vl = 0.f, il = 0.f, mx = -1e30f;
    for (int t = 0; t < SEQ; t++) {
        float a = a3[(size_t)t * (BSZ * NO) + idx];
        float vn = vl + DVM * (il - vl);
        il = DIS * il + a;
        vl = vn;
        mx = fmaxf(mx, vl + 0.001f * noise[(size_t)t * (BSZ * NO) + idx]);
    }
    out[idx] = mx;
}

// ---------------- host ----------------
extern "C" void kernel_launch(void* const* d_in, const int* in_sizes, int n_in,
                              void* d_out, int out_size, void* d_ws, size_t ws_size,
                              hipStream_t stream) {
    const float* x     = (const float*)d_in[0];
    const float* W1    = (const float*)d_in[1];
    const float* b1    = (const float*)d_in[2];
    const float* W2    = (const float*)d_in[3];
    const float* b2    = (const float*)d_in[4];
    const float* W3    = (const float*)d_in[5];
    const float* b3    = (const float*)d_in[6];
    const float* noise = (const float*)d_in[7];
    float* out = (float*)d_out;

    char* ws = (char*)d_ws;
    float* inp1 = (float*)(ws + OFF_INP1);
    float* a2   = (float*)(ws + OFF_A2);
    float* a3   = (float*)(ws + OFF_A3);
    unsigned short* xf  = (unsigned short*)(ws + OFF_XF);
    unsigned short* w1f = (unsigned short*)(ws + OFF_W1F);
    unsigned long long* z1 = (unsigned long long*)(ws + OFF_Z1);
    float* v2 = (float*)(ws + OFF_V2);
    float* i2 = (float*)(ws + OFF_I2);
    unsigned long long* z2 = (unsigned long long*)(ws + OFF_Z2);
    unsigned short* w2f = (unsigned short*)(ws + OFF_W2F);

    dim3 blk(256);
    prep_x_kernel<<<dim3(6144), blk, 0, stream>>>(x, xf);
    prep_w1_kernel<<<dim3(2304), blk, 0, stream>>>(W1, w1f);
    prep_w2_kernel<<<dim3(192), blk, 0, stream>>>(W2, w2f);
    gemm1_mfma<<<dim3(768), blk, 0, stream>>>(xf, w1f, b1, inp1);
    lif1_kernel<<<dim3(N1/256, BSZ), blk, 0, stream>>>(inp1, z1);   // z1 overlays xf (dead)
    for (int c = 0; c < NCHUNK; c++) {
        gemm2_mfma<<<dim3(256, 2), blk, 0, stream>>>(z1, w2f, b2, a2, c);
        lif2z_kernel<<<dim3(BSZ), blk, 0, stream>>>(a2, v2, i2, z2, c);  // v2/i2/z2 overlay w1f (dead)
    }
    gemm3_kernel<<<dim3(SEQ * BSZ / 256), blk, 0, stream>>>(z2, W3, b3, a3);
    li_kernel<<<dim3((BSZ * NO + 255) / 256), blk, 0, stream>>>(a3, noise, out);
}

// Round 11
// 984.708 us; speedup vs baseline: 1.4640x; 1.2349x over previous
//
#include <hip/hip_runtime.h>

// ---------------- problem constants ----------------
#define BSZ   4096
#define NIN   3072
#define N1    1536
#define N2    256
#define NO    10
#define SEQ   128
#define CH    16            // timesteps per chunk
#define NCHUNK (SEQ/CH)

// dynamics constants
#define DVM  0.1f           // DT*TAU_MEM_INV
#define DIS  0.8f           // 1 - DT*TAU_SYN_INV
#define VTH  0.4f

// W2 int8 2-digit quantization scales: W2 = S1*q1 + S2*q2, |q|<=127
// S1 = 1/(127*sqrt(1536)) (uniform-init bound / 127), S2 = S1/254.
// MUST be identical literals in prep and epilogue.
#define W2S1 2.0090963e-04f
#define W2S2 7.9098279e-07f

// ---------------- workspace layout (bytes) ----------------
// [0, 67108864)        : inp1 (25MB) -> a2 (67MB per chunk) -> a3 (21MB)
// [67108864, ...)      : xfrag (75.5MB, dead after gemm1)  UNION  z1d (100.7MB)
// [167772160, ...)     : w1frag (28.3MB, dead after gemm1) UNION  v2+i2+z2 (25.2MB)
// [196083712, ...)     : w2q (768KB) ; end < 199229440
#define OFF_INP1 0
#define OFF_A2   0
#define OFF_A3   0
#define OFF_XF   67108864
#define OFF_Z1   67108864
#define OFF_W1F  167772160
#define OFF_V2   167772160
#define OFF_I2   171966464
#define OFF_Z2   176160768
#define OFF_W2F  196083712

typedef short bf16x8 __attribute__((ext_vector_type(8)));
typedef float f32x4  __attribute__((ext_vector_type(4)));
typedef int   i32x4  __attribute__((ext_vector_type(4)));

__device__ __forceinline__ void gload_lds16(const unsigned short* g, unsigned short* l) {
    __builtin_amdgcn_global_load_lds(
        (const __attribute__((address_space(1))) unsigned int*)g,
        (__attribute__((address_space(3))) unsigned int*)l, 16, 0, 0);
}

__device__ __forceinline__ unsigned short rne_bf16(float x) {
    unsigned u = __float_as_uint(x);
    return (unsigned short)((u + 0x7FFFu + ((u >> 16) & 1u)) >> 16);
}
__device__ __forceinline__ float bf2f(unsigned short h) {
    return __uint_as_float(((unsigned)h) << 16);
}

// ============ prep_x: 3-digit bf16 split of x, MFMA-fragment order ============
__global__ __launch_bounds__(256) void prep_x_kernel(
        const float* __restrict__ x, unsigned short* __restrict__ xf) {
    const int idx = blockIdx.x * 256 + threadIdx.x;
    const int lane = idx & 63;
    const int m16 = (idx >> 6) & 255;
    const int ks  = idx >> 14;                 // 0..95
    const int row = m16 * 16 + (lane & 15);
    const int k0  = ks * 32 + (lane >> 4) * 8;
    const float* src = x + (size_t)row * NIN + k0;
    union { unsigned short u[8]; bf16x8 v; } h, m, l;
    #pragma unroll
    for (int j = 0; j < 8; j++) {
        float v = src[j];
        h.u[j] = rne_bf16(v);
        float r1 = v - bf2f(h.u[j]);
        m.u[j] = rne_bf16(r1);
        float r2 = r1 - bf2f(m.u[j]);
        l.u[j] = rne_bf16(r2);
    }
    unsigned short* dst = xf + ((size_t)(ks * 256 + m16) * 3) * 512 + lane * 8;
    *(bf16x8*)(dst)        = h.v;
    *(bf16x8*)(dst + 512)  = m.v;
    *(bf16x8*)(dst + 1024) = l.v;
}

// ============ prep_w1: 3-digit split of W1, fragment order for LDS staging ============
__global__ __launch_bounds__(256) void prep_w1_kernel(
        const float* __restrict__ W1, unsigned short* __restrict__ wf) {
    const int idx = blockIdx.x * 256 + threadIdx.x;
    const int ks  = idx / 6144;                // 0..95
    const int rem = idx % 6144;
    const int n16 = rem >> 6;                  // 0..95
    const int lane = rem & 63;
    const int row = n16 * 16 + (lane & 15);
    const int k0  = ks * 32 + (lane >> 4) * 8;
    const float* src = W1 + (size_t)row * NIN + k0;
    union { unsigned short u[8]; bf16x8 v; } h, m, l;
    #pragma unroll
    for (int j = 0; j < 8; j++) {
        float v = src[j];
        h.u[j] = rne_bf16(v);
        float r1 = v - bf2f(h.u[j]);
        m.u[j] = rne_bf16(r1);
        float r2 = r1 - bf2f(m.u[j]);
        l.u[j] = rne_bf16(r2);
    }
    unsigned short* dst = wf + ((size_t)ks * 12 + (n16 >> 3)) * 12288
                             + (n16 & 7) * 1536 + lane * 8;
    *(bf16x8*)(dst)        = h.v;
    *(bf16x8*)(dst + 512)  = m.v;
    *(bf16x8*)(dst + 1024) = l.v;
}

// ============ GEMM1 via MFMA: inp1 = x @ W1.T + b1, 6-product digit split ============
__global__ __launch_bounds__(256, 3) void gemm1_mfma(
        const unsigned short* __restrict__ xf, const unsigned short* __restrict__ w1f,
        const float* __restrict__ b1, float* __restrict__ inp1) {
    __shared__ unsigned short Bs[2][12288];    // 2 x 24 KB
    const int tx = threadIdx.x;
    const int wave = tx >> 6, lane = tx & 63;
    const int wm = wave >> 1, wn = wave & 1;
    const int ln = lane & 15, ko = lane >> 4;
    const int bid = blockIdx.x;                // 768 blocks
    const int wg = (bid & 7) * 96 + (bid >> 3);   // XCD-chunked swizzle (768%8==0)
    const int mtile = wg / 12, ntile = wg % 12;   // mtile 0..63
    const int m16b = mtile * 4 + wm * 2;

    f32x4 acc[2][4];
    #pragma unroll
    for (int mt = 0; mt < 2; mt++)
        #pragma unroll
        for (int nt = 0; nt < 4; nt++) acc[mt][nt] = (f32x4){0.f,0.f,0.f,0.f};

    const unsigned short* xfr = xf + lane * 8;

#define ALOAD(A_, ks_) do {                                                   \
    _Pragma("unroll")                                                         \
    for (int mt_ = 0; mt_ < 2; mt_++)                                         \
        _Pragma("unroll")                                                     \
        for (int d_ = 0; d_ < 3; d_++)                                        \
            A_[mt_][d_] = *(const bf16x8*)(xfr +                              \
                (((size_t)(ks_) * 256 + m16b + mt_) * 3 + d_) * 512);         \
} while (0)

#define STAGE1(ks_, buf_) do {                                                \
    const unsigned short* s_ = w1f + ((size_t)(ks_) * 12 + ntile) * 12288     \
                                   + wave * 3072 + lane * 8;                  \
    unsigned short* d_ = &Bs[buf_][wave * 3072];                              \
    _Pragma("unroll")                                                         \
    for (int j_ = 0; j_ < 6; j_++)                                            \
        gload_lds16(s_ + j_ * 512, d_ + j_ * 512);                            \
} while (0)

#define COMPUTE(A_, buf_) do {                                                \
    _Pragma("unroll")                                                         \
    for (int nt_ = 0; nt_ < 4; nt_++) {                                       \
        const unsigned short* bp_ = &Bs[buf_][(wn * 4 + nt_) * 1536 + lane * 8]; \
        bf16x8 bh_ = *(const bf16x8*)(bp_);                                   \
        bf16x8 bm_ = *(const bf16x8*)(bp_ + 512);                             \
        bf16x8 bl_ = *(const bf16x8*)(bp_ + 1024);                            \
        _Pragma("unroll")                                                     \
        for (int mt_ = 0; mt_ < 2; mt_++) {                                   \
            acc[mt_][nt_] = __builtin_amdgcn_mfma_f32_16x16x32_bf16(A_[mt_][0], bh_, acc[mt_][nt_], 0, 0, 0); \
            acc[mt_][nt_] = __builtin_amdgcn_mfma_f32_16x16x32_bf16(A_[mt_][1], bh_, acc[mt_][nt_], 0, 0, 0); \
            acc[mt_][nt_] = __builtin_amdgcn_mfma_f32_16x16x32_bf16(A_[mt_][2], bh_, acc[mt_][nt_], 0, 0, 0); \
            acc[mt_][nt_] = __builtin_amdgcn_mfma_f32_16x16x32_bf16(A_[mt_][0], bm_, acc[mt_][nt_], 0, 0, 0); \
            acc[mt_][nt_] = __builtin_amdgcn_mfma_f32_16x16x32_bf16(A_[mt_][1], bm_, acc[mt_][nt_], 0, 0, 0); \
            acc[mt_][nt_] = __builtin_amdgcn_mfma_f32_16x16x32_bf16(A_[mt_][0], bl_, acc[mt_][nt_], 0, 0, 0); \
        }                                                                     \
    }                                                                         \
} while (0)

    bf16x8 aA[2][3], aB[2][3];
    ALOAD(aA, 0);
    STAGE1(0, 0);
    __syncthreads();

    for (int ks = 0; ks < 96; ks += 2) {
        STAGE1(ks + 1, 1);
        ALOAD(aB, ks + 1);
        COMPUTE(aA, 0);
        __syncthreads();
        if (ks + 2 < 96) {
            STAGE1(ks + 2, 0);
            ALOAD(aA, ks + 2);
        }
        COMPUTE(aB, 1);
        __syncthreads();
    }

    #pragma unroll
    for (int nt = 0; nt < 4; nt++) {
        const int n = ntile * 128 + wn * 64 + nt * 16 + ln;
        const float bias = b1[n];
        #pragma unroll
        for (int mt = 0; mt < 2; mt++) {
            #pragma unroll
            for (int r = 0; r < 4; r++) {
                const int m = mtile * 64 + wm * 32 + mt * 16 + ko * 4 + r;
                inp1[(size_t)m * N1 + n] = acc[mt][nt][r] + bias;
            }
        }
    }
#undef ALOAD
#undef STAGE1
#undef COMPUTE
}

// ============ LIF1: ballot-free; per-thread bit accumulate + 64x64 wave bit-transpose
__global__ __launch_bounds__(256) void lif1_kernel(
        const float* __restrict__ inp1, unsigned long long* __restrict__ z1d) {
    const int b = blockIdx.y;
    const int n = blockIdx.x * 256 + threadIdx.x;
    const int lane = threadIdx.x & 63;
    const int w = n >> 6;                      // word index 0..23
    const float inp = inp1[(size_t)b * N1 + n];
    float v = 0.f, i = 0.f;
    unsigned int u[4];
    #pragma unroll
    for (int s = 0; s < 4; s++) {
        unsigned int acc = 0;
        #pragma unroll
        for (int k = 0; k < 32; k++) {
            float vd = v + DVM * (i - v);
            bool z = (vd - VTH) > 0.f;
            acc = (acc << 1) | (z ? 1u : 0u);
            v = z ? 0.f : vd;
            i = DIS * i + inp;
        }
        u[s] = acc;
    }
    unsigned long long X0 = ((unsigned long long)u[0] << 32) | u[1];
    unsigned long long X1 = ((unsigned long long)u[2] << 32) | u[3];
    #pragma unroll
    for (int s = 0; s < 6; s++) {
        const int j = 32 >> s;
        const unsigned long long m =
            (s == 0) ? 0x00000000FFFFFFFFull :
            (s == 1) ? 0x0000FFFF0000FFFFull :
            (s == 2) ? 0x00FF00FF00FF00FFull :
            (s == 3) ? 0x0F0F0F0F0F0F0F0Full :
            (s == 4) ? 0x3333333333333333ull : 0x5555555555555555ull;
        unsigned long long p0 = __shfl_xor(X0, j, 64);
        unsigned long long p1 = __shfl_xor(X1, j, 64);
        if (lane & j) {
            X0 = (X0 & m) | ((p0 << j) & ~m);
            X1 = (X1 & m) | ((p1 << j) & ~m);
        } else {
            X0 = (X0 & ~m) | ((p0 >> j) & m);
            X1 = (X1 & ~m) | ((p1 >> j) & m);
        }
    }
    unsigned long long Y0 = ((unsigned long long)__builtin_bitreverse32((unsigned int)X0) << 32)
                          | __builtin_bitreverse32((unsigned int)(X0 >> 32));
    unsigned long long Y1 = ((unsigned long long)__builtin_bitreverse32((unsigned int)X1) << 32)
                          | __builtin_bitreverse32((unsigned int)(X1 >> 32));
    const int bg = b >> 7, bl = b & 127;
    unsigned long long* zb = z1d + ((size_t)(bg * 24 + w) * 128) * 128 + bl;
    zb[(size_t)lane * 128]        = Y0;        // t = lane
    zb[(size_t)(64 + lane) * 128] = Y1;        // t = 64 + lane
}

// ============ W2 prep: 2-digit int8 quantization in i8-MFMA fragment order ============
// byte addr = (w*2+nblk)*16384 + nt8*2048 + digit*1024 + lane*16 + j
// value = q_digit[ n = (nblk*8+nt8)*16 + (lane&15) ][ k = w*64 + (lane>>4)*16 + j ]
__global__ __launch_bounds__(256) void prep_w2_i8(
        const float* __restrict__ W2, signed char* __restrict__ frag) {
    const int idx = blockIdx.x * 256 + threadIdx.x;   // 96 blocks
    const int lane = idx & 63;
    const int nt8  = (idx >> 6) & 7;
    const int chunk = idx >> 9;                        // 0..47  (w*2+nblk)
    const int nblk = chunk & 1, w = chunk >> 1;
    const int n = (nblk * 8 + nt8) * 16 + (lane & 15);
    const int k0 = w * 64 + (lane >> 4) * 16;
    const float* src = W2 + (size_t)n * N1 + k0;
    union { signed char c[16]; i32x4 v; } q1, q2;
    #pragma unroll
    for (int j = 0; j < 16; j++) {
        float x = src[j];
        int a = (int)rintf(x * (1.0f / W2S1));
        a = a > 127 ? 127 : (a < -127 ? -127 : a);
        float r = x - (float)a * W2S1;
        int b = (int)rintf(r * (1.0f / W2S2));
        b = b > 127 ? 127 : (b < -127 ? -127 : b);
        q1.c[j] = (signed char)a;
        q2.c[j] = (signed char)b;
    }
    signed char* dst = frag + (size_t)chunk * 16384 + nt8 * 2048 + lane * 16;
    *(i32x4*)(dst)        = q1.v;
    *(i32x4*)(dst + 1024) = q2.v;
}

// ============ GEMM2 via i8 MFMA (K=64): a2 = z1 @ (S1*q1 + S2*q2).T + b2 ============
// block 256 thr = 4 waves (2M x 2N); block tile 128M x 128N; wave 64M x 64N (mt=4,nt=4)
// One spike u64 word = one full K=64 MFMA. i32 accumulation exact.
__global__ __launch_bounds__(256, 2) void gemm2_i8(
        const unsigned long long* __restrict__ z1d,
        const signed char* __restrict__ w2q,
        const float* __restrict__ b2, float* __restrict__ a2, int c) {
    __shared__ signed char Bs[2][16384];
    const int tx = threadIdx.x;
    const int wave = tx >> 6, lane = tx & 63;
    const int wm = wave >> 1, wn = wave & 1;
    const int ko = lane >> 4, ln = lane & 15;
    const int bm = blockIdx.x;                 // 0..511
    const int bn = blockIdx.y;                 // 0..1
    const int t_l = bm >> 5;                   // 0..15
    const int b0 = (bm & 31) * 128 + wm * 64;
    const int t  = c * CH + t_l;

    i32x4 acc[4][4][2];
    #pragma unroll
    for (int mt = 0; mt < 4; mt++)
        #pragma unroll
        for (int nt = 0; nt < 4; nt++)
            #pragma unroll
            for (int d = 0; d < 2; d++) acc[mt][nt][d] = (i32x4){0,0,0,0};

    const int bg = b0 >> 7;
    const size_t zbase2 = ((size_t)(bg * 24) * 128 + t) * 128 + (b0 & 127) + ln;
    const signed char* sgbase = w2q + (size_t)bn * 16384 + wave * 4096 + lane * 16;

    #define STAGE_B(w_, buf_) do {                                           \
        const signed char* s_ = sgbase + (size_t)(w_) * 32768;               \
        signed char* d_ = &Bs[buf_][wave * 4096];                            \
        _Pragma("unroll")                                                    \
        for (int j_ = 0; j_ < 4; j_++)                                       \
            gload_lds16((const unsigned short*)(s_ + j_ * 1024),             \
                        (unsigned short*)(d_ + j_ * 1024));                  \
    } while (0)

    #define LOADZ(Z_, w_) do {                                               \
        _Pragma("unroll")                                                    \
        for (int mt_ = 0; mt_ < 4; mt_++)                                    \
            Z_[mt_] = z1d[zbase2 + (size_t)(w_) * 16384 + mt_ * 16];         \
    } while (0)

    // expand 16 spike bits (k = ko*16..+15) -> 16 i8 {0,1} via nibble spread
    #define COMP(Z_, buf_) do {                                              \
        i32x4 af[4];                                                         \
        _Pragma("unroll")                                                    \
        for (int mt_ = 0; mt_ < 4; mt_++) {                                  \
            unsigned int bits = (unsigned int)(Z_[mt_] >> (ko * 16)) & 0xFFFFu; \
            _Pragma("unroll")                                                \
            for (int j4 = 0; j4 < 4; j4++) {                                 \
                unsigned int nib = (bits >> (j4 * 4)) & 0xFu;                \
                af[mt_][j4] = (int)((nib * 0x00204081u) & 0x01010101u);      \
            }                                                                \
        }                                                                    \
        _Pragma("unroll")                                                    \
        for (int nt_ = 0; nt_ < 4; nt_++) {                                  \
            const signed char* bp_ = &Bs[buf_][(wn * 4 + nt_) * 2048 + lane * 16]; \
            i32x4 bq0 = *(const i32x4*)(bp_);                                \
            i32x4 bq1 = *(const i32x4*)(bp_ + 1024);                         \
            _Pragma("unroll")                                                \
            for (int mt_ = 0; mt_ < 4; mt_++) {                              \
                acc[mt_][nt_][0] = __builtin_amdgcn_mfma_i32_16x16x64_i8(af[mt_], bq0, acc[mt_][nt_][0], 0, 0, 0); \
                acc[mt_][nt_][1] = __builtin_amdgcn_mfma_i32_16x16x64_i8(af[mt_], bq1, acc[mt_][nt_][1], 0, 0, 0); \
            }                                                                \
        }                                                                    \
    } while (0)

    unsigned long long zwA[4], zwB[4];
    LOADZ(zwA, 0);
    STAGE_B(0, 0);
    __syncthreads();

    for (int w = 0; w < 24; w += 2) {
        LOADZ(zwB, w + 1);
        STAGE_B(w + 1, 1);
        COMP(zwA, 0);
        __syncthreads();
        if (w + 2 < 24) {
            LOADZ(zwA, w + 2);
            STAGE_B(w + 2, 0);
        }
        COMP(zwB, 1);
        __syncthreads();
    }

    // epilogue: C/D col=lane&15, row=(lane>>4)*4+r ; a2 = S1*acc1 + S2*acc2 + bias
    #pragma unroll
    for (int nt = 0; nt < 4; nt++) {
        const int o = bn * 128 + (wn * 4 + nt) * 16 + ln;
        const float bias = b2[o];
        #pragma unroll
        for (int mt = 0; mt < 4; mt++) {
            #pragma unroll
            for (int r = 0; r < 4; r++) {
                const int brow = b0 + mt * 16 + ko * 4 + r;
                float val = fmaf((float)acc[mt][nt][0][r], W2S1,
                            fmaf((float)acc[mt][nt][1][r], W2S2, bias));
                a2[((size_t)t_l * BSZ + brow) * N2 + o] = val;
            }
        }
    }
    #undef STAGE_B
    #undef LOADZ
    #undef COMP
}

// ============ LIF2 spikes only (a2 prefetched) ============
__global__ __launch_bounds__(256) void lif2z_kernel(
        const float* __restrict__ a2, float* __restrict__ v2s, float* __restrict__ i2s,
        unsigned long long* __restrict__ z2bits, int c) {
    const int b = blockIdx.x;
    const int n = threadIdx.x;
    const int wid = n >> 6, lane = n & 63;
    float av[CH];
    #pragma unroll
    for (int tl = 0; tl < CH; tl++)
        av[tl] = a2[((size_t)tl * BSZ + b) * N2 + n];
    float v2, i2;
    if (c == 0) { v2 = 0.f; i2 = 0.f; }
    else { v2 = v2s[(size_t)b * N2 + n]; i2 = i2s[(size_t)b * N2 + n]; }
    #pragma unroll
    for (int tl = 0; tl < CH; tl++) {
        float vd = v2 + DVM * (i2 - v2);
        bool z = (vd - VTH) > 0.f;
        unsigned long long m = __ballot(z);
        if (lane == 0) z2bits[((size_t)(c * CH + tl) * BSZ + b) * 4 + wid] = m;
        v2 = z ? 0.f : vd;
        i2 = DIS * i2 + av[tl];
    }
    v2s[(size_t)b * N2 + n] = v2;
    i2s[(size_t)b * N2 + n] = i2;
}

// ============ GEMM3: a3 = z2 @ W3.T + b3 (bit-dot) ============
__global__ __launch_bounds__(256) void gemm3_kernel(
        const unsigned long long* __restrict__ z2bits, const float* __restrict__ W3,
        const float* __restrict__ b3, float* __restrict__ a3) {
    const int idx = blockIdx.x * 256 + threadIdx.x;
    unsigned long long zw[4];
    #pragma unroll
    for (int g = 0; g < 4; g++) zw[g] = z2bits[(size_t)idx * 4 + g];
    float acc[NO];
    #pragma unroll
    for (int o = 0; o < NO; o++) acc[o] = b3[o];
    #pragma unroll
    for (int g = 0; g < 4; g++) {
        unsigned long long wg = zw[g];
        for (int kb = 0; kb < 64; kb++) {
            float bit = (float)((wg >> kb) & 1ull);
            #pragma unroll
            for (int o = 0; o < NO; o++)
                acc[o] = fmaf(bit, W3[o * N2 + g * 64 + kb], acc[o]);
        }
    }
    #pragma unroll
    for (int o = 0; o < NO; o++) a3[(size_t)idx * NO + o] = acc[o];
}

// ============ LI + max over time ============
__global__ __launch_bounds__(256) void li_kernel(
        const float* __restrict__ a3, const float* __restrict__ noise,
        float* __restrict__ out) {
    const int idx = blockIdx.x * 256 + threadIdx.x;
    if (idx >= BSZ * NO) return;
    float vl = 0.f, il = 0.f, mx = -1e30f;
    for (int t = 0; t < SEQ; t++) {
        float a = a3[(size_t)t * (BSZ * NO) + idx];
        float vn = vl + DVM * (il - vl);
        il = DIS * il + a;
        vl = vn;
        mx = fmaxf(mx, vl + 0.001f * noise[(size_t)t * (BSZ * NO) + idx]);
    }
    out[idx] = mx;
}

// ---------------- host ----------------
extern "C" void kernel_launch(void* const* d_in, const int* in_sizes, int n_in,
                              void* d_out, int out_size, void* d_ws, size_t ws_size,
                              hipStream_t stream) {
    const float* x     = (const float*)d_in[0];
    const float* W1    = (const float*)d_in[1];
    const float* b1    = (const float*)d_in[2];
    const float* W2    = (const float*)d_in[3];
    const float* b2    = (const float*)d_in[4];
    const float* W3    = (const float*)d_in[5];
    const float* b3    = (const float*)d_in[6];
    const float* noise = (const float*)d_in[7];
    float* out = (float*)d_out;

    char* ws = (char*)d_ws;
    float* inp1 = (float*)(ws + OFF_INP1);
    float* a2   = (float*)(ws + OFF_A2);
    float* a3   = (float*)(ws + OFF_A3);
    unsigned short* xf  = (unsigned short*)(ws + OFF_XF);
    unsigned short* w1f = (unsigned short*)(ws + OFF_W1F);
    unsigned long long* z1 = (unsigned long long*)(ws + OFF_Z1);
    float* v2 = (float*)(ws + OFF_V2);
    float* i2 = (float*)(ws + OFF_I2);
    unsigned long long* z2 = (unsigned long long*)(ws + OFF_Z2);
    signed char* w2q = (signed char*)(ws + OFF_W2F);

    dim3 blk(256);
    prep_x_kernel<<<dim3(6144), blk, 0, stream>>>(x, xf);
    prep_w1_kernel<<<dim3(2304), blk, 0, stream>>>(W1, w1f);
    prep_w2_i8<<<dim3(96), blk, 0, stream>>>(W2, w2q);
    gemm1_mfma<<<dim3(768), blk, 0, stream>>>(xf, w1f, b1, inp1);
    lif1_kernel<<<dim3(N1/256, BSZ), blk, 0, stream>>>(inp1, z1);   // z1 overlays xf (dead)
    for (int c = 0; c < NCHUNK; c++) {
        gemm2_i8<<<dim3(512, 2), blk, 0, stream>>>(z1, w2q, b2, a2, c);
        lif2z_kernel<<<dim3(BSZ), blk, 0, stream>>>(a2, v2, i2, z2, c);  // v2/i2/z2 overlay w1f (dead)
    }
    gemm3_kernel<<<dim3(SEQ * BSZ / 256), blk, 0, stream>>>(z2, W3, b3, a3);
    li_kernel<<<dim3((BSZ * NO + 255) / 256), blk, 0, stream>>>(a3, noise, out);
}

// Round 12
// 901.226 us; speedup vs baseline: 1.5996x; 1.0926x over previous
//
#include <hip/hip_runtime.h>

// ---------------- problem constants ----------------
#define BSZ   4096
#define NIN   3072
#define N1    1536
#define N2    256
#define NO    10
#define SEQ   128
#define CH    16            // timesteps per chunk
#define NCHUNK (SEQ/CH)

// dynamics constants
#define DVM  0.1f           // DT*TAU_MEM_INV
#define DIS  0.8f           // 1 - DT*TAU_SYN_INV
#define VTH  0.4f

// W2 int8 2-digit quantization scales (unchanged, proven R11)
#define W2S1 2.0090963e-04f
#define W2S2 7.9098279e-07f

// x 3-digit i8 scales: S1X = 6/127 (clamp +-6 sigma), chain /254
#define S1X 4.7244094e-02f
#define S2X 1.8600037e-04f
#define S3X 7.3228492e-07f
// W1 3-digit i8 scales: S1W = (1/sqrt(3072))/127, chain /254
#define S1W 1.4206453e-04f
#define S2W 5.5931704e-07f
#define S3W 2.2020356e-09f

// ---------------- workspace layout (bytes) ----------------
// [0, 67108864)        : inp1 (25MB) -> a2 (67MB per chunk) -> a3 (21MB)
// [67108864, ...)      : xq (37.7MB, dead after gemm1)  UNION  z1d (100.7MB)
// [167772160, ...)     : w1q (14.2MB, dead after gemm1) UNION  v2+i2+z2 (25.2MB)
// [196083712, ...)     : w2q (768KB) ; end < 199229440
#define OFF_INP1 0
#define OFF_A2   0
#define OFF_A3   0
#define OFF_XF   67108864
#define OFF_Z1   67108864
#define OFF_W1F  167772160
#define OFF_V2   167772160
#define OFF_I2   171966464
#define OFF_Z2   176160768
#define OFF_W2F  196083712

typedef short bf16x8 __attribute__((ext_vector_type(8)));
typedef float f32x4  __attribute__((ext_vector_type(4)));
typedef int   i32x4  __attribute__((ext_vector_type(4)));

__device__ __forceinline__ void gload_lds16(const unsigned short* g, unsigned short* l) {
    __builtin_amdgcn_global_load_lds(
        (const __attribute__((address_space(1))) unsigned int*)g,
        (__attribute__((address_space(3))) unsigned int*)l, 16, 0, 0);
}

__device__ __forceinline__ int q8(float v, float inv) {
    int a = (int)rintf(v * inv);
    return a > 127 ? 127 : (a < -127 ? -127 : a);
}

// ============ prep_x_i8: 3-digit base-254 int8 split of x, i8-MFMA fragment order ====
// chunk(ks 0..47, m16 0..255): [digit 0..2][lane][16B] = 3 KB
// value = dig_d( x[m16*16 + (lane&15)][ks*64 + (lane>>4)*16 + j] )
__global__ __launch_bounds__(256) void prep_x_i8(
        const float* __restrict__ x, signed char* __restrict__ xq) {
    const int idx = blockIdx.x * 256 + threadIdx.x;   // 3072 blocks
    const int lane = idx & 63;
    const int m16 = (idx >> 6) & 255;
    const int ks  = idx >> 14;                         // 0..47
    const int row = m16 * 16 + (lane & 15);
    const int k0  = ks * 64 + (lane >> 4) * 16;
    const float* src = x + (size_t)row * NIN + k0;
    union { signed char c[16]; i32x4 v; } q1, q2, q3;
    #pragma unroll
    for (int j = 0; j < 16; j++) {
        float v = src[j];
        v = fminf(fmaxf(v, -6.f), 6.f);
        int a = q8(v, 1.0f / S1X);
        float r1 = fmaf((float)(-a), S1X, v);
        int b = q8(r1, 1.0f / S2X);
        float r2 = fmaf((float)(-b), S2X, r1);
        int c = q8(r2, 1.0f / S3X);
        q1.c[j] = (signed char)a; q2.c[j] = (signed char)b; q3.c[j] = (signed char)c;
    }
    signed char* dst = xq + (size_t)(ks * 256 + m16) * 3072 + lane * 16;
    *(i32x4*)(dst)        = q1.v;
    *(i32x4*)(dst + 1024) = q2.v;
    *(i32x4*)(dst + 2048) = q3.v;
}

// ============ prep_w1_i8: 3-digit int8 split of W1, fragment order for LDS staging ====
// chunk(ks 0..47, ntile 0..11) = 24576 B: [nt8 0..7][digit 0..2][lane][16B]
__global__ __launch_bounds__(256) void prep_w1_i8(
        const float* __restrict__ W1, signed char* __restrict__ w1q) {
    const int idx = blockIdx.x * 256 + threadIdx.x;   // 1152 blocks
    const int ks  = idx / 6144;                        // 0..47
    const int rem = idx % 6144;
    const int n16 = rem >> 6;                          // 0..95
    const int lane = rem & 63;
    const int row = n16 * 16 + (lane & 15);
    const int k0  = ks * 64 + (lane >> 4) * 16;
    const float* src = W1 + (size_t)row * NIN + k0;
    union { signed char c[16]; i32x4 v; } q1, q2, q3;
    #pragma unroll
    for (int j = 0; j < 16; j++) {
        float v = src[j];
        int a = q8(v, 1.0f / S1W);
        float r1 = fmaf((float)(-a), S1W, v);
        int b = q8(r1, 1.0f / S2W);
        float r2 = fmaf((float)(-b), S2W, r1);
        int c = q8(r2, 1.0f / S3W);
        q1.c[j] = (signed char)a; q2.c[j] = (signed char)b; q3.c[j] = (signed char)c;
    }
    signed char* dst = w1q + ((size_t)ks * 12 + (n16 >> 3)) * 24576
                           + (n16 & 7) * 3072 + lane * 16;
    *(i32x4*)(dst)        = q1.v;
    *(i32x4*)(dst + 1024) = q2.v;
    *(i32x4*)(dst + 2048) = q3.v;
}

// ============ GEMM1 via i8 MFMA (K=64): inp1 = x @ W1.T + b1 ============
// 6 digit-products collapse to 3 i32 accumulators (equal-scale tiers):
//   A0 = d1e1 ; A1 = d1e2 + d2e1 ; A2 = d1e3 + d2e2 + d3e1
//   inp1 = S1X*S1W * (A0 + A1/254 + A2/254^2) + bias
// block 256 thr = 4 waves (2m x 2n); tile 64M x 128N; grid 768 (3 blocks/CU)
__global__ __launch_bounds__(256, 3) void gemm1_i8(
        const signed char* __restrict__ xq, const signed char* __restrict__ w1q,
        const float* __restrict__ b1, float* __restrict__ inp1) {
    __shared__ signed char Bs[2][24576];    // 2 x 24 KB
    const int tx = threadIdx.x;
    const int wave = tx >> 6, lane = tx & 63;
    const int wm = wave >> 1, wn = wave & 1;
    const int ln = lane & 15, ko = lane >> 4;
    const int bid = blockIdx.x;                   // 768 blocks
    const int wg = (bid & 7) * 96 + (bid >> 3);   // XCD-chunked swizzle (768%8==0)
    const int mtile = wg / 12, ntile = wg % 12;
    const int m16b = mtile * 4 + wm * 2;

    i32x4 acc[2][4][3];
    #pragma unroll
    for (int mt = 0; mt < 2; mt++)
        #pragma unroll
        for (int nt = 0; nt < 4; nt++)
            #pragma unroll
            for (int d = 0; d < 3; d++) acc[mt][nt][d] = (i32x4){0,0,0,0};

    const signed char* xbase = xq + lane * 16;

#define ALOADI(A_, ks_) do {                                                  \
    _Pragma("unroll")                                                         \
    for (int mt_ = 0; mt_ < 2; mt_++)                                         \
        _Pragma("unroll")                                                     \
        for (int d_ = 0; d_ < 3; d_++)                                        \
            A_[mt_][d_] = *(const i32x4*)(xbase +                             \
                (size_t)((ks_) * 256 + m16b + mt_) * 3072 + d_ * 1024);       \
} while (0)

#define STAGEI(ks_, buf_) do {                                                \
    const signed char* s_ = w1q + ((size_t)(ks_) * 12 + ntile) * 24576        \
                                + wave * 6144 + lane * 16;                    \
    signed char* d_ = &Bs[buf_][wave * 6144];                                 \
    _Pragma("unroll")                                                         \
    for (int j_ = 0; j_ < 6; j_++)                                            \
        gload_lds16((const unsigned short*)(s_ + j_ * 1024),                  \
                    (unsigned short*)(d_ + j_ * 1024));                       \
} while (0)

#define COMPI(A_, buf_) do {                                                  \
    _Pragma("unroll")                                                         \
    for (int nt_ = 0; nt_ < 4; nt_++) {                                       \
        const signed char* bp_ = &Bs[buf_][(wn * 4 + nt_) * 3072 + lane * 16];\
        i32x4 e1 = *(const i32x4*)(bp_);                                      \
        i32x4 e2 = *(const i32x4*)(bp_ + 1024);                               \
        i32x4 e3 = *(const i32x4*)(bp_ + 2048);                               \
        _Pragma("unroll")                                                     \
        for (int mt_ = 0; mt_ < 2; mt_++) {                                   \
            acc[mt_][nt_][0] = __builtin_amdgcn_mfma_i32_16x16x64_i8(A_[mt_][0], e1, acc[mt_][nt_][0], 0, 0, 0); \
            acc[mt_][nt_][1] = __builtin_amdgcn_mfma_i32_16x16x64_i8(A_[mt_][0], e2, acc[mt_][nt_][1], 0, 0, 0); \
            acc[mt_][nt_][1] = __builtin_amdgcn_mfma_i32_16x16x64_i8(A_[mt_][1], e1, acc[mt_][nt_][1], 0, 0, 0); \
            acc[mt_][nt_][2] = __builtin_amdgcn_mfma_i32_16x16x64_i8(A_[mt_][0], e3, acc[mt_][nt_][2], 0, 0, 0); \
            acc[mt_][nt_][2] = __builtin_amdgcn_mfma_i32_16x16x64_i8(A_[mt_][1], e2, acc[mt_][nt_][2], 0, 0, 0); \
            acc[mt_][nt_][2] = __builtin_amdgcn_mfma_i32_16x16x64_i8(A_[mt_][2], e1, acc[mt_][nt_][2], 0, 0, 0); \
        }                                                                     \
    }                                                                         \
} while (0)

    i32x4 aA[2][3];
    STAGEI(0, 0);
    __syncthreads();

    for (int ks = 0; ks < 48; ks++) {
        const int buf = ks & 1;
        ALOADI(aA, ks);                 // issued before stage -> waits at vmcnt(6)
        if (ks + 1 < 48) STAGEI(ks + 1, buf ^ 1);
        COMPI(aA, buf);
        __syncthreads();
    }

    // epilogue: C/D col=lane&15, row=(lane>>4)*4+r
    const float S11 = S1X * S1W;
    #pragma unroll
    for (int nt = 0; nt < 4; nt++) {
        const int n = ntile * 128 + wn * 64 + nt * 16 + ln;
        const float bias = b1[n];
        #pragma unroll
        for (int mt = 0; mt < 2; mt++) {
            #pragma unroll
            for (int r = 0; r < 4; r++) {
                const int m = mtile * 64 + wm * 32 + mt * 16 + ko * 4 + r;
                float f = (float)acc[mt][nt][0][r]
                        + (1.0f / 254.0f)   * (float)acc[mt][nt][1][r]
                        + (1.0f / 64516.0f) * (float)acc[mt][nt][2][r];
                inp1[(size_t)m * N1 + n] = fmaf(f, S11, bias);
            }
        }
    }
#undef ALOADI
#undef STAGEI
#undef COMPI
}

// ============ LIF1: ballot-free; per-thread bit accumulate + 64x64 wave bit-transpose
__global__ __launch_bounds__(256) void lif1_kernel(
        const float* __restrict__ inp1, unsigned long long* __restrict__ z1d) {
    const int b = blockIdx.y;
    const int n = blockIdx.x * 256 + threadIdx.x;
    const int lane = threadIdx.x & 63;
    const int w = n >> 6;                      // word index 0..23
    const float inp = inp1[(size_t)b * N1 + n];
    float v = 0.f, i = 0.f;
    unsigned int u[4];
    #pragma unroll
    for (int s = 0; s < 4; s++) {
        unsigned int acc = 0;
        #pragma unroll
        for (int k = 0; k < 32; k++) {
            float vd = v + DVM * (i - v);
            bool z = (vd - VTH) > 0.f;
            acc = (acc << 1) | (z ? 1u : 0u);
            v = z ? 0.f : vd;
            i = DIS * i + inp;
        }
        u[s] = acc;
    }
    unsigned long long X0 = ((unsigned long long)u[0] << 32) | u[1];
    unsigned long long X1 = ((unsigned long long)u[2] << 32) | u[3];
    #pragma unroll
    for (int s = 0; s < 6; s++) {
        const int j = 32 >> s;
        const unsigned long long m =
            (s == 0) ? 0x00000000FFFFFFFFull :
            (s == 1) ? 0x0000FFFF0000FFFFull :
            (s == 2) ? 0x00FF00FF00FF00FFull :
            (s == 3) ? 0x0F0F0F0F0F0F0F0Full :
            (s == 4) ? 0x3333333333333333ull : 0x5555555555555555ull;
        unsigned long long p0 = __shfl_xor(X0, j, 64);
        unsigned long long p1 = __shfl_xor(X1, j, 64);
        if (lane & j) {
            X0 = (X0 & m) | ((p0 << j) & ~m);
            X1 = (X1 & m) | ((p1 << j) & ~m);
        } else {
            X0 = (X0 & ~m) | ((p0 >> j) & m);
            X1 = (X1 & ~m) | ((p1 >> j) & m);
        }
    }
    unsigned long long Y0 = ((unsigned long long)__builtin_bitreverse32((unsigned int)X0) << 32)
                          | __builtin_bitreverse32((unsigned int)(X0 >> 32));
    unsigned long long Y1 = ((unsigned long long)__builtin_bitreverse32((unsigned int)X1) << 32)
                          | __builtin_bitreverse32((unsigned int)(X1 >> 32));
    const int bg = b >> 7, bl = b & 127;
    unsigned long long* zb = z1d + ((size_t)(bg * 24 + w) * 128) * 128 + bl;
    zb[(size_t)lane * 128]        = Y0;        // t = lane
    zb[(size_t)(64 + lane) * 128] = Y1;        // t = 64 + lane
}

// ============ W2 prep: 2-digit int8 quantization in i8-MFMA fragment order ============
__global__ __launch_bounds__(256) void prep_w2_i8(
        const float* __restrict__ W2, signed char* __restrict__ frag) {
    const int idx = blockIdx.x * 256 + threadIdx.x;   // 96 blocks
    const int lane = idx & 63;
    const int nt8  = (idx >> 6) & 7;
    const int chunk = idx >> 9;                        // 0..47  (w*2+nblk)
    const int nblk = chunk & 1, w = chunk >> 1;
    const int n = (nblk * 8 + nt8) * 16 + (lane & 15);
    const int k0 = w * 64 + (lane >> 4) * 16;
    const float* src = W2 + (size_t)n * N1 + k0;
    union { signed char c[16]; i32x4 v; } q1, q2;
    #pragma unroll
    for (int j = 0; j < 16; j++) {
        float x = src[j];
        int a = (int)rintf(x * (1.0f / W2S1));
        a = a > 127 ? 127 : (a < -127 ? -127 : a);
        float r = x - (float)a * W2S1;
        int b = (int)rintf(r * (1.0f / W2S2));
        b = b > 127 ? 127 : (b < -127 ? -127 : b);
        q1.c[j] = (signed char)a;
        q2.c[j] = (signed char)b;
    }
    signed char* dst = frag + (size_t)chunk * 16384 + nt8 * 2048 + lane * 16;
    *(i32x4*)(dst)        = q1.v;
    *(i32x4*)(dst + 1024) = q2.v;
}

// ============ GEMM2 via i8 MFMA (K=64): a2 = z1 @ (S1*q1 + S2*q2).T + b2 ============
__global__ __launch_bounds__(256, 2) void gemm2_i8(
        const unsigned long long* __restrict__ z1d,
        const signed char* __restrict__ w2q,
        const float* __restrict__ b2, float* __restrict__ a2, int c) {
    __shared__ signed char Bs[2][16384];
    const int tx = threadIdx.x;
    const int wave = tx >> 6, lane = tx & 63;
    const int wm = wave >> 1, wn = wave & 1;
    const int ko = lane >> 4, ln = lane & 15;
    const int bm = blockIdx.x;                 // 0..511
    const int bn = blockIdx.y;                 // 0..1
    const int t_l = bm >> 5;                   // 0..15
    const int b0 = (bm & 31) * 128 + wm * 64;
    const int t  = c * CH + t_l;

    i32x4 acc[4][4][2];
    #pragma unroll
    for (int mt = 0; mt < 4; mt++)
        #pragma unroll
        for (int nt = 0; nt < 4; nt++)
            #pragma unroll
            for (int d = 0; d < 2; d++) acc[mt][nt][d] = (i32x4){0,0,0,0};

    const int bg = b0 >> 7;
    const size_t zbase2 = ((size_t)(bg * 24) * 128 + t) * 128 + (b0 & 127) + ln;
    const signed char* sgbase = w2q + (size_t)bn * 16384 + wave * 4096 + lane * 16;

    #define STAGE_B(w_, buf_) do {                                           \
        const signed char* s_ = sgbase + (size_t)(w_) * 32768;               \
        signed char* d_ = &Bs[buf_][wave * 4096];                            \
        _Pragma("unroll")                                                    \
        for (int j_ = 0; j_ < 4; j_++)                                       \
            gload_lds16((const unsigned short*)(s_ + j_ * 1024),             \
                        (unsigned short*)(d_ + j_ * 1024));                  \
    } while (0)

    #define LOADZ(Z_, w_) do {                                               \
        _Pragma("unroll")                                                    \
        for (int mt_ = 0; mt_ < 4; mt_++)                                    \
            Z_[mt_] = z1d[zbase2 + (size_t)(w_) * 16384 + mt_ * 16];         \
    } while (0)

    #define COMP(Z_, buf_) do {                                              \
        i32x4 af[4];                                                         \
        _Pragma("unroll")                                                    \
        for (int mt_ = 0; mt_ < 4; mt_++) {                                  \
            unsigned int bits = (unsigned int)(Z_[mt_] >> (ko * 16)) & 0xFFFFu; \
            _Pragma("unroll")                                                \
            for (int j4 = 0; j4 < 4; j4++) {                                 \
                unsigned int nib = (bits >> (j4 * 4)) & 0xFu;                \
                af[mt_][j4] = (int)((nib * 0x00204081u) & 0x01010101u);      \
            }                                                                \
        }                                                                    \
        _Pragma("unroll")                                                    \
        for (int nt_ = 0; nt_ < 4; nt_++) {                                  \
            const signed char* bp_ = &Bs[buf_][(wn * 4 + nt_) * 2048 + lane * 16]; \
            i32x4 bq0 = *(const i32x4*)(bp_);                                \
            i32x4 bq1 = *(const i32x4*)(bp_ + 1024);                         \
            _Pragma("unroll")                                                \
            for (int mt_ = 0; mt_ < 4; mt_++) {                              \
                acc[mt_][nt_][0] = __builtin_amdgcn_mfma_i32_16x16x64_i8(af[mt_], bq0, acc[mt_][nt_][0], 0, 0, 0); \
                acc[mt_][nt_][1] = __builtin_amdgcn_mfma_i32_16x16x64_i8(af[mt_], bq1, acc[mt_][nt_][1], 0, 0, 0); \
            }                                                                \
        }                                                                    \
    } while (0)

    unsigned long long zwA[4], zwB[4];
    LOADZ(zwA, 0);
    STAGE_B(0, 0);
    __syncthreads();

    for (int w = 0; w < 24; w += 2) {
        LOADZ(zwB, w + 1);
        STAGE_B(w + 1, 1);
        COMP(zwA, 0);
        __syncthreads();
        if (w + 2 < 24) {
            LOADZ(zwA, w + 2);
            STAGE_B(w + 2, 0);
        }
        COMP(zwB, 1);
        __syncthreads();
    }

    #pragma unroll
    for (int nt = 0; nt < 4; nt++) {
        const int o = bn * 128 + (wn * 4 + nt) * 16 + ln;
        const float bias = b2[o];
        #pragma unroll
        for (int mt = 0; mt < 4; mt++) {
            #pragma unroll
            for (int r = 0; r < 4; r++) {
                const int brow = b0 + mt * 16 + ko * 4 + r;
                float val = fmaf((float)acc[mt][nt][0][r], W2S1,
                            fmaf((float)acc[mt][nt][1][r], W2S2, bias));
                a2[((size_t)t_l * BSZ + brow) * N2 + o] = val;
            }
        }
    }
    #undef STAGE_B
    #undef LOADZ
    #undef COMP
}

// ============ LIF2 spikes only (a2 prefetched) ============
__global__ __launch_bounds__(256) void lif2z_kernel(
        const float* __restrict__ a2, float* __restrict__ v2s, float* __restrict__ i2s,
        unsigned long long* __restrict__ z2bits, int c) {
    const int b = blockIdx.x;
    const int n = threadIdx.x;
    const int wid = n >> 6, lane = n & 63;
    float av[CH];
    #pragma unroll
    for (int tl = 0; tl < CH; tl++)
        av[tl] = a2[((size_t)tl * BSZ + b) * N2 + n];
    float v2, i2;
    if (c == 0) { v2 = 0.f; i2 = 0.f; }
    else { v2 = v2s[(size_t)b * N2 + n]; i2 = i2s[(size_t)b * N2 + n]; }
    #pragma unroll
    for (int tl = 0; tl < CH; tl++) {
        float vd = v2 + DVM * (i2 - v2);
        bool z = (vd - VTH) > 0.f;
        unsigned long long m = __ballot(z);
        if (lane == 0) z2bits[((size_t)(c * CH + tl) * BSZ + b) * 4 + wid] = m;
        v2 = z ? 0.f : vd;
        i2 = DIS * i2 + av[tl];
    }
    v2s[(size_t)b * N2 + n] = v2;
    i2s[(size_t)b * N2 + n] = i2;
}

// ============ GEMM3: a3 = z2 @ W3.T + b3 (bit-dot) ============
__global__ __launch_bounds__(256) void gemm3_kernel(
        const unsigned long long* __restrict__ z2bits, const float* __restrict__ W3,
        const float* __restrict__ b3, float* __restrict__ a3) {
    const int idx = blockIdx.x * 256 + threadIdx.x;
    unsigned long long zw[4];
    #pragma unroll
    for (int g = 0; g < 4; g++) zw[g] = z2bits[(size_t)idx * 4 + g];
    float acc[NO];
    #pragma unroll
    for (int o = 0; o < NO; o++) acc[o] = b3[o];
    #pragma unroll
    for (int g = 0; g < 4; g++) {
        unsigned long long wg = zw[g];
        for (int kb = 0; kb < 64; kb++) {
            float bit = (float)((wg >> kb) & 1ull);
            #pragma unroll
            for (int o = 0; o < NO; o++)
                acc[o] = fmaf(bit, W3[o * N2 + g * 64 + kb], acc[o]);
        }
    }
    #pragma unroll
    for (int o = 0; o < NO; o++) a3[(size_t)idx * NO + o] = acc[o];
}

// ============ LI + max over time ============
__global__ __launch_bounds__(256) void li_kernel(
        const float* __restrict__ a3, const float* __restrict__ noise,
        float* __restrict__ out) {
    const int idx = blockIdx.x * 256 + threadIdx.x;
    if (idx >= BSZ * NO) return;
    float vl = 0.f, il = 0.f, mx = -1e30f;
    for (int t = 0; t < SEQ; t++) {
        float a = a3[(size_t)t * (BSZ * NO) + idx];
        float vn = vl + DVM * (il - vl);
        il = DIS * il + a;
        vl = vn;
        mx = fmaxf(mx, vl + 0.001f * noise[(size_t)t * (BSZ * NO) + idx]);
    }
    out[idx] = mx;
}

// ---------------- host ----------------
extern "C" void kernel_launch(void* const* d_in, const int* in_sizes, int n_in,
                              void* d_out, int out_size, void* d_ws, size_t ws_size,
                              hipStream_t stream) {
    const float* x     = (const float*)d_in[0];
    const float* W1    = (const float*)d_in[1];
    const float* b1    = (const float*)d_in[2];
    const float* W2    = (const float*)d_in[3];
    const float* b2    = (const float*)d_in[4];
    const float* W3    = (const float*)d_in[5];
    const float* b3    = (const float*)d_in[6];
    const float* noise = (const float*)d_in[7];
    float* out = (float*)d_out;

    char* ws = (char*)d_ws;
    float* inp1 = (float*)(ws + OFF_INP1);
    float* a2   = (float*)(ws + OFF_A2);
    float* a3   = (float*)(ws + OFF_A3);
    signed char* xq  = (signed char*)(ws + OFF_XF);
    signed char* w1q = (signed char*)(ws + OFF_W1F);
    unsigned long long* z1 = (unsigned long long*)(ws + OFF_Z1);
    float* v2 = (float*)(ws + OFF_V2);
    float* i2 = (float*)(ws + OFF_I2);
    unsigned long long* z2 = (unsigned long long*)(ws + OFF_Z2);
    signed char* w2q = (signed char*)(ws + OFF_W2F);

    dim3 blk(256);
    prep_x_i8<<<dim3(3072), blk, 0, stream>>>(x, xq);
    prep_w1_i8<<<dim3(1152), blk, 0, stream>>>(W1, w1q);
    prep_w2_i8<<<dim3(96), blk, 0, stream>>>(W2, w2q);
    gemm1_i8<<<dim3(768), blk, 0, stream>>>(xq, w1q, b1, inp1);
    lif1_kernel<<<dim3(N1/256, BSZ), blk, 0, stream>>>(inp1, z1);   // z1 overlays xq (dead)
    for (int c = 0; c < NCHUNK; c++) {
        gemm2_i8<<<dim3(512, 2), blk, 0, stream>>>(z1, w2q, b2, a2, c);
        lif2z_kernel<<<dim3(BSZ), blk, 0, stream>>>(a2, v2, i2, z2, c);  // v2/i2/z2 overlay w1q (dead)
    }
    gemm3_kernel<<<dim3(SEQ * BSZ / 256), blk, 0, stream>>>(z2, W3, b3, a3);
    li_kernel<<<dim3((BSZ * NO + 255) / 256), blk, 0, stream>>>(a3, noise, out);
}